// Round 1
// baseline (339.303 us; speedup 1.0000x reference)
//
#include <hip/hip_runtime.h>
#include <stdint.h>

typedef unsigned short u16;
typedef __attribute__((ext_vector_type(8))) short frag8;   // 8 bf16 (4 VGPRs)
typedef __attribute__((ext_vector_type(4))) float fx4;     // 4 fp32 acc

#define MFMA(a, b, c) __builtin_amdgcn_mfma_f32_16x16x32_bf16((a), (b), (c), 0, 0, 0)

__device__ __forceinline__ u16 f2bf(float f) {
  union { float f; unsigned int u; } c; c.f = f;
  unsigned int r = c.u + 0x7FFFu + ((c.u >> 16) & 1u);  // RNE
  return (u16)(r >> 16);
}

// ---------------- conversions ----------------

__global__ __launch_bounds__(256) void cvt_x(const float* __restrict__ x, u16* __restrict__ xb) {
  const int n4 = (8192 * 1024) / 4;
  for (int i = blockIdx.x * 256 + threadIdx.x; i < n4; i += 2048 * 256) {
    float4 v = ((const float4*)x)[i];
    ushort4 o;
    o.x = f2bf(v.x); o.y = f2bf(v.y); o.z = f2bf(v.z); o.w = f2bf(v.w);
    ((ushort4*)xb)[i] = o;
  }
}

// Wq/Wk/Wv [H][C][D] -> Wt [(type*16+h)*64+d][c]  (N=3072 rows, K=1024)
__global__ __launch_bounds__(256) void cvt_wqkv(const float* __restrict__ Wq,
                                                const float* __restrict__ Wk,
                                                const float* __restrict__ Wv,
                                                u16* __restrict__ Wt) {
  __shared__ u16 Tls[64][72];  // +pad
  int hh = blockIdx.x;            // 0..47
  int c0 = blockIdx.y * 64;
  int type = hh >> 4, h = hh & 15;
  const float* Wsrc = (type == 0 ? Wq : (type == 1 ? Wk : Wv)) + (size_t)h * 1024 * 64;
  int t = threadIdx.x;
  int cr = t >> 4, q4 = (t & 15) * 4;
  for (int i = 0; i < 4; ++i) {
    int c = cr + i * 16;
    float4 v = *(const float4*)(Wsrc + (size_t)(c0 + c) * 64 + q4);
    Tls[q4 + 0][c] = f2bf(v.x);
    Tls[q4 + 1][c] = f2bf(v.y);
    Tls[q4 + 2][c] = f2bf(v.z);
    Tls[q4 + 3][c] = f2bf(v.w);
  }
  __syncthreads();
  for (int i = 0; i < 4; ++i) {
    int d = cr + i * 16;
    ushort4 o;
    o.x = Tls[d][q4 + 0]; o.y = Tls[d][q4 + 1]; o.z = Tls[d][q4 + 2]; o.w = Tls[d][q4 + 3];
    *(ushort4*)(Wt + ((size_t)hh * 64 + d) * 1024 + c0 + q4) = o;
  }
}

__global__ __launch_bounds__(256) void cvt_wp(const float* __restrict__ Wp, u16* __restrict__ wb) {
  const int n4 = (1024 * 1024) / 4;
  for (int i = blockIdx.x * 256 + threadIdx.x; i < n4; i += 1024 * 256) {
    float4 v = ((const float4*)Wp)[i];
    ushort4 o;
    o.x = f2bf(v.x); o.y = f2bf(v.y); o.z = f2bf(v.z); o.w = f2bf(v.w);
    ((ushort4*)wb)[i] = o;
  }
}

// ---------------- GEMM: C[m][n] = sum_k A[m][k] * Bw[n][k], K=1024 ----------------
// MODE 0: scatter bf16 to Q/K/V [B][H][T][D].  MODE 1: +bias, fp32 out.

template <int MODE>
__global__ __launch_bounds__(256) void gemm_bt(const u16* __restrict__ A, const u16* __restrict__ Bw,
                                               u16* __restrict__ Qb, u16* __restrict__ Kb,
                                               u16* __restrict__ Vb, float* __restrict__ outp,
                                               const float* __restrict__ bp) {
  __shared__ u16 As[128 * 32];
  __shared__ u16 Bs[128 * 32];
  int tid = threadIdx.x;
  int m0 = blockIdx.x * 128, n0 = blockIdx.y * 128;
  int wid = tid >> 6, lane = tid & 63, lr = lane & 15, lg = lane >> 4;
  int wm = (wid >> 1) * 64, wn = (wid & 1) * 64;
  const u16* Ag = A + (size_t)m0 * 1024;
  const u16* Bg = Bw + (size_t)n0 * 1024;
  int r0 = tid >> 2, c0 = tid & 3;
  int sto0 = r0 * 64 + ((c0 * 16) ^ ((r0 & 3) << 4));
  int sto1 = (r0 + 64) * 64 + ((c0 * 16) ^ ((r0 & 3) << 4));
  int aoff[4], boff[4];
#pragma unroll
  for (int i = 0; i < 4; ++i) {
    aoff[i] = (wm + i * 16 + lr) * 64 + ((lg * 16) ^ ((lr & 3) << 4));
    boff[i] = (wn + i * 16 + lr) * 64 + ((lg * 16) ^ ((lr & 3) << 4));
  }
  fx4 acc[4][4] = {};
  for (int kt = 0; kt < 32; ++kt) {
    const u16* ak = Ag + kt * 32;
    const u16* bk = Bg + kt * 32;
    frag8 a0 = *(const frag8*)(ak + (size_t)r0 * 1024 + c0 * 8);
    frag8 a1 = *(const frag8*)(ak + (size_t)(r0 + 64) * 1024 + c0 * 8);
    frag8 b0 = *(const frag8*)(bk + (size_t)r0 * 1024 + c0 * 8);
    frag8 b1 = *(const frag8*)(bk + (size_t)(r0 + 64) * 1024 + c0 * 8);
    __syncthreads();
    *(frag8*)((char*)As + sto0) = a0;
    *(frag8*)((char*)As + sto1) = a1;
    *(frag8*)((char*)Bs + sto0) = b0;
    *(frag8*)((char*)Bs + sto1) = b1;
    __syncthreads();
    frag8 af[4], bf_[4];
#pragma unroll
    for (int i = 0; i < 4; ++i) af[i] = *(const frag8*)((const char*)As + aoff[i]);
#pragma unroll
    for (int i = 0; i < 4; ++i) bf_[i] = *(const frag8*)((const char*)Bs + boff[i]);
#pragma unroll
    for (int mi = 0; mi < 4; ++mi)
#pragma unroll
      for (int ni = 0; ni < 4; ++ni) acc[mi][ni] = MFMA(af[mi], bf_[ni], acc[mi][ni]);
  }
#pragma unroll
  for (int mi = 0; mi < 4; ++mi)
#pragma unroll
    for (int r = 0; r < 4; ++r) {
      int m = m0 + wm + mi * 16 + lg * 4 + r;
      if (MODE == 0) {
        int b = m >> 11, t = m & 2047;
#pragma unroll
        for (int ni = 0; ni < 4; ++ni) {
          int n = n0 + wn + ni * 16 + lr;
          int type = n >> 10, h = (n >> 6) & 15, d = n & 63;
          u16* dst = (type == 0) ? Qb : ((type == 1) ? Kb : Vb);
          dst[((size_t)(b * 16 + h) * 2048 + t) * 64 + d] = f2bf(acc[mi][ni][r]);
        }
      } else {
#pragma unroll
        for (int ni = 0; ni < 4; ++ni) {
          int n = n0 + wn + ni * 16 + lr;
          outp[(size_t)m * 1024 + n] = acc[mi][ni][r] + bp[n];
        }
      }
    }
}

// ---------------- flash attention ----------------
// grid (T/64, B*H); 4 waves, each owns 16 q-rows. KV tile = 64.

__global__ __launch_bounds__(256) void attn(const u16* __restrict__ Qb, const u16* __restrict__ Kb,
                                            const u16* __restrict__ Vb, u16* __restrict__ Ao,
                                            const int* __restrict__ mflag) {
  __shared__ u16 Ks[64 * 64];       // [s][d], XOR-swizzled
  __shared__ u16 Vs[64 * 64];       // transposed [d][s], XOR-swizzled
  __shared__ u16 Ps[4][16 * 64];    // per-wave P tile
  int tid = threadIdx.x, wid = tid >> 6, lane = tid & 63, lr = lane & 15, lg = lane >> 4;
  int qt = blockIdx.x, bh = blockIdx.y;
  int masked = mflag[0];
  int qbase = qt * 64;
  const u16* Qh = Qb + (size_t)bh * 2048 * 64;
  const u16* Kh = Kb + (size_t)bh * 2048 * 64;
  const u16* Vh = Vb + (size_t)bh * 2048 * 64;
  int qrow = qbase + wid * 16 + lr;
  frag8 qf0 = *(const frag8*)(Qh + (size_t)qrow * 64 + lg * 8);
  frag8 qf1 = *(const frag8*)(Qh + (size_t)qrow * 64 + 32 + lg * 8);
  float m_run[4] = {-__builtin_inff(), -__builtin_inff(), -__builtin_inff(), -__builtin_inff()};
  float l_run[4] = {0.f, 0.f, 0.f, 0.f};
  fx4 oacc[4] = {};
  u16* Pw = &Ps[wid][0];
  int vs_s = tid & 63, vs_d0 = (tid >> 6) * 16;
  int ntiles = masked ? (qt + 1) : 32;
  for (int kt = 0; kt < ntiles; ++kt) {
    int s0 = kt * 64;
    __syncthreads();
    {  // K tile: 512 16B chunks, 2 per thread
      int idx = tid, s_ = idx >> 3, c_ = idx & 7;
      frag8 v = *(const frag8*)(Kh + (size_t)(s0 + s_) * 64 + c_ * 8);
      *(frag8*)((char*)Ks + s_ * 128 + ((c_ * 16) ^ ((s_ & 7) << 4))) = v;
      idx = tid + 256; s_ = idx >> 3; c_ = idx & 7;
      frag8 v2 = *(const frag8*)(Kh + (size_t)(s0 + s_) * 64 + c_ * 8);
      *(frag8*)((char*)Ks + s_ * 128 + ((c_ * 16) ^ ((s_ & 7) << 4))) = v2;
    }
    {  // V tile transposed: each thread one s-row, 16 d
      frag8 v0 = *(const frag8*)(Vh + (size_t)(s0 + vs_s) * 64 + vs_d0);
      frag8 v1 = *(const frag8*)(Vh + (size_t)(s0 + vs_s) * 64 + vs_d0 + 8);
      int sl = (vs_s & 7) * 2, sh = vs_s >> 3;
#pragma unroll
      for (int j = 0; j < 8; ++j) {
        int d = vs_d0 + j;
        *(u16*)((char*)Vs + d * 128 + 16 * (sh ^ (d & 7)) + sl) = (u16)v0[j];
        d = vs_d0 + 8 + j;
        *(u16*)((char*)Vs + d * 128 + 16 * (sh ^ (d & 7)) + sl) = (u16)v1[j];
      }
    }
    __syncthreads();
    // S = Q K^T
    fx4 sc[4];
#pragma unroll
    for (int nt = 0; nt < 4; ++nt) {
      int srow = nt * 16 + lr;
      frag8 k0 = *(const frag8*)((const char*)Ks + srow * 128 + ((lg * 16) ^ ((srow & 7) << 4)));
      frag8 k1 = *(const frag8*)((const char*)Ks + srow * 128 + ((64 + lg * 16) ^ ((srow & 7) << 4)));
      fx4 a = {};
      a = MFMA(qf0, k0, a);
      a = MFMA(qf1, k1, a);
      sc[nt] = a;
    }
    const float scale = 0.03125f;  // 1/sqrt(C=1024)
#pragma unroll
    for (int nt = 0; nt < 4; ++nt)
#pragma unroll
      for (int r = 0; r < 4; ++r) sc[nt][r] *= scale;
    if (masked && kt == qt) {
#pragma unroll
      for (int nt = 0; nt < 4; ++nt) {
        int col = nt * 16 + lr;
#pragma unroll
        for (int r = 0; r < 4; ++r) {
          int rowl = wid * 16 + lg * 4 + r;
          if (col > rowl) sc[nt][r] = -__builtin_inff();
        }
      }
    }
    // online softmax, rows live in 16-lane groups
    float alpha[4];
#pragma unroll
    for (int r = 0; r < 4; ++r) {
      float mx = fmaxf(fmaxf(sc[0][r], sc[1][r]), fmaxf(sc[2][r], sc[3][r]));
      mx = fmaxf(mx, __shfl_xor(mx, 1));
      mx = fmaxf(mx, __shfl_xor(mx, 2));
      mx = fmaxf(mx, __shfl_xor(mx, 4));
      mx = fmaxf(mx, __shfl_xor(mx, 8));
      float mn = fmaxf(m_run[r], mx);
      float ps = 0.f;
#pragma unroll
      for (int nt = 0; nt < 4; ++nt) {
        float p = __expf(sc[nt][r] - mn);
        sc[nt][r] = p;
        ps += p;
      }
      ps += __shfl_xor(ps, 1);
      ps += __shfl_xor(ps, 2);
      ps += __shfl_xor(ps, 4);
      ps += __shfl_xor(ps, 8);
      float al = __expf(m_run[r] - mn);
      alpha[r] = al;
      m_run[r] = mn;
      l_run[r] = l_run[r] * al + ps;
    }
#pragma unroll
    for (int nt = 0; nt < 4; ++nt)
#pragma unroll
      for (int r = 0; r < 4; ++r) oacc[nt][r] *= alpha[r];
    // P -> wave-private LDS (acc layout -> A-frag layout)
#pragma unroll
    for (int nt = 0; nt < 4; ++nt) {
      int pcol = nt * 16 + lr;
#pragma unroll
      for (int r = 0; r < 4; ++r) {
        int prow = lg * 4 + r;
        *(u16*)((char*)Pw + prow * 128 + ((pcol * 2) ^ ((prow & 7) << 4))) = f2bf(sc[nt][r]);
      }
    }
    frag8 pf0 = *(const frag8*)((const char*)Pw + lr * 128 + ((lg * 16) ^ ((lr & 7) << 4)));
    frag8 pf1 = *(const frag8*)((const char*)Pw + lr * 128 + ((64 + lg * 16) ^ ((lr & 7) << 4)));
#pragma unroll
    for (int nt = 0; nt < 4; ++nt) {
      int d_ = nt * 16 + lr;
      frag8 vf0 = *(const frag8*)((const char*)Vs + d_ * 128 + 16 * ((0 + lg) ^ (d_ & 7)));
      frag8 vf1 = *(const frag8*)((const char*)Vs + d_ * 128 + 16 * ((4 + lg) ^ (d_ & 7)));
      oacc[nt] = MFMA(pf0, vf0, oacc[nt]);
      oacc[nt] = MFMA(pf1, vf1, oacc[nt]);
    }
  }
  int b = bh >> 4, h = bh & 15;
#pragma unroll
  for (int r = 0; r < 4; ++r) {
    float inv = 1.0f / l_run[r];
    int rowg = qbase + wid * 16 + lg * 4 + r;
    size_t base = ((size_t)b * 2048 + rowg) * 1024 + h * 64;
#pragma unroll
    for (int nt = 0; nt < 4; ++nt) Ao[base + nt * 16 + lr] = f2bf(oacc[nt][r] * inv);
  }
}

// ---------------- launch ----------------

extern "C" void kernel_launch(void* const* d_in, const int* in_sizes, int n_in,
                              void* d_out, int out_size, void* d_ws, size_t ws_size,
                              hipStream_t stream) {
  const float* x = (const float*)d_in[0];
  const float* Wq = (const float*)d_in[1];
  const float* Wk = (const float*)d_in[2];
  const float* Wv = (const float*)d_in[3];
  const float* Wp = (const float*)d_in[4];
  const float* bp = (const float*)d_in[5];
  const int* is_masked = (const int*)d_in[6];
  float* out = (float*)d_out;
  char* ws = (char*)d_ws;
  u16* Xbf = (u16*)(ws + 0);              // 16 MB
  u16* Wt  = (u16*)(ws + 16777216);       // 6 MB
  u16* Wpb = (u16*)(ws + 23068672);       // 2 MB
  u16* Qb  = (u16*)(ws + 25165824);       // 16 MB
  u16* Kb  = (u16*)(ws + 41943040);       // 16 MB
  u16* Vb  = (u16*)(ws + 58720256);       // 16 MB
  u16* Ao  = (u16*)(ws + 75497472);       // 16 MB

  cvt_x<<<2048, 256, 0, stream>>>(x, Xbf);
  cvt_wqkv<<<dim3(48, 16), 256, 0, stream>>>(Wq, Wk, Wv, Wt);
  cvt_wp<<<1024, 256, 0, stream>>>(Wp, Wpb);
  gemm_bt<0><<<dim3(64, 24), 256, 0, stream>>>(Xbf, Wt, Qb, Kb, Vb, nullptr, nullptr);
  attn<<<dim3(32, 64), 256, 0, stream>>>(Qb, Kb, Vb, Ao, is_masked);
  gemm_bt<1><<<dim3(64, 8), 256, 0, stream>>>(Ao, Wpb, nullptr, nullptr, nullptr, out, bp);
}

// Round 2
// 197.236 us; speedup vs baseline: 1.7203x; 1.7203x over previous
//
#include <hip/hip_runtime.h>
#include <stdint.h>

typedef unsigned short u16;
typedef unsigned int u32;
typedef __attribute__((ext_vector_type(8))) short frag8;   // 8 bf16 (4 VGPRs)
typedef __attribute__((ext_vector_type(4))) float fx4;     // 4 fp32 acc
typedef __attribute__((ext_vector_type(4))) u32 u32x4;

#define MFMA(a, b, c) __builtin_amdgcn_mfma_f32_16x16x32_bf16((a), (b), (c), 0, 0, 0)

__device__ __forceinline__ void gload16(const void* g, void* l) {
  __builtin_amdgcn_global_load_lds((const __attribute__((address_space(1))) void*)g,
                                   (__attribute__((address_space(3))) void*)l, 16, 0, 0);
}

__device__ __forceinline__ u16 f2bf(float f) {
  union { float f; unsigned int u; } c; c.f = f;
  unsigned int r = c.u + 0x7FFFu + ((c.u >> 16) & 1u);  // RNE
  return (u16)(r >> 16);
}

__device__ __forceinline__ u32 cvtpk(float lo, float hi) {
  u32 r;
  asm("v_cvt_pk_bf16_f32 %0, %1, %2" : "=v"(r) : "v"(lo), "v"(hi));
  return r;
}

// ---------------- conversions ----------------

__global__ __launch_bounds__(256) void cvt_x(const float* __restrict__ x, u16* __restrict__ xb) {
  const int n4 = (8192 * 1024) / 4;
  for (int i = blockIdx.x * 256 + threadIdx.x; i < n4; i += 2048 * 256) {
    float4 v = ((const float4*)x)[i];
    ushort4 o;
    o.x = f2bf(v.x); o.y = f2bf(v.y); o.z = f2bf(v.z); o.w = f2bf(v.w);
    ((ushort4*)xb)[i] = o;
  }
}

// Wq/Wk/Wv [H][C][D] -> Wt [(type*16+h)*64+d][c]  (N=3072 rows, K=1024)
__global__ __launch_bounds__(256) void cvt_wqkv(const float* __restrict__ Wq,
                                                const float* __restrict__ Wk,
                                                const float* __restrict__ Wv,
                                                u16* __restrict__ Wt) {
  __shared__ u16 Tls[64][72];  // +pad
  int hh = blockIdx.x;            // 0..47
  int c0 = blockIdx.y * 64;
  int type = hh >> 4, h = hh & 15;
  const float* Wsrc = (type == 0 ? Wq : (type == 1 ? Wk : Wv)) + (size_t)h * 1024 * 64;
  int t = threadIdx.x;
  int cr = t >> 4, q4 = (t & 15) * 4;
  for (int i = 0; i < 4; ++i) {
    int c = cr + i * 16;
    float4 v = *(const float4*)(Wsrc + (size_t)(c0 + c) * 64 + q4);
    Tls[q4 + 0][c] = f2bf(v.x);
    Tls[q4 + 1][c] = f2bf(v.y);
    Tls[q4 + 2][c] = f2bf(v.z);
    Tls[q4 + 3][c] = f2bf(v.w);
  }
  __syncthreads();
  for (int i = 0; i < 4; ++i) {
    int d = cr + i * 16;
    ushort4 o;
    o.x = Tls[d][q4 + 0]; o.y = Tls[d][q4 + 1]; o.z = Tls[d][q4 + 2]; o.w = Tls[d][q4 + 3];
    *(ushort4*)(Wt + ((size_t)hh * 64 + d) * 1024 + c0 + q4) = o;
  }
}

__global__ __launch_bounds__(256) void cvt_wp(const float* __restrict__ Wp, u16* __restrict__ wb) {
  const int n4 = (1024 * 1024) / 4;
  for (int i = blockIdx.x * 256 + threadIdx.x; i < n4; i += 1024 * 256) {
    float4 v = ((const float4*)Wp)[i];
    ushort4 o;
    o.x = f2bf(v.x); o.y = f2bf(v.y); o.z = f2bf(v.z); o.w = f2bf(v.w);
    ((ushort4*)wb)[i] = o;
  }
}

// V [bh][2048][64] -> VT [bh][64][2048]
__global__ __launch_bounds__(256) void transpose_v(const u16* __restrict__ Vb, u16* __restrict__ VTg) {
  __shared__ u16 T[64 * 64];  // chunk-XOR swizzled rows of 128B
  int bh = blockIdx.x, t0 = blockIdx.y * 64;
  const u16* src = Vb + ((size_t)bh * 2048 + t0) * 64;
  int tid = threadIdx.x;
  int tl = tid >> 2, c16 = (tid & 3) * 16;
  int swzw = (tl & 7) << 4;
  frag8 a = *(const frag8*)(src + (size_t)tl * 64 + c16);
  frag8 b = *(const frag8*)(src + (size_t)tl * 64 + c16 + 8);
  *(frag8*)((char*)T + tl * 128 + ((c16 * 2) ^ swzw)) = a;
  *(frag8*)((char*)T + tl * 128 + ((c16 * 2 + 16) ^ swzw)) = b;
  __syncthreads();
  int d_ = tid & 63;
#pragma unroll
  for (int k = 0; k < 2; ++k) {
    int c_ = (tid >> 6) + 4 * k;
    frag8 o;
#pragma unroll
    for (int j = 0; j < 8; ++j) {
      int t = c_ * 8 + j;
      o[j] = *(const u16*)((const char*)T + t * 128 + ((2 * d_) ^ ((t & 7) << 4)));
    }
    *(frag8*)(VTg + ((size_t)bh * 64 + d_) * 2048 + t0 + c_ * 8) = o;
  }
}

// ---------------- GEMM: C[m][n] = sum_k A[m][k] * Bw[n][k], K=1024 ----------------
// Staging via global_load_lds w=16, linear LDS dest + inverse-swizzled global src.

template <int MODE>
__global__ __launch_bounds__(256) void gemm_bt(const u16* __restrict__ A, const u16* __restrict__ Bw,
                                               u16* __restrict__ Qb, u16* __restrict__ Kb,
                                               u16* __restrict__ Vb, float* __restrict__ outp,
                                               const float* __restrict__ bp) {
  __shared__ u16 As[128 * 32];
  __shared__ u16 Bs[128 * 32];
  int tid = threadIdx.x;
  int m0 = blockIdx.x * 128, n0 = blockIdx.y * 128;
  int wid = tid >> 6, lane = tid & 63, lr = lane & 15, lg = lane >> 4;
  int wm = (wid >> 1) * 64, wn = (wid & 1) * 64;
  const u16* Ag = A + (size_t)m0 * 1024;
  const u16* Bg = Bw + (size_t)n0 * 1024;
  // staging: wave issues calls c=0,1; 16 rows per call; chunk = (lane&3)^(row&3)
  int cidx0 = wid * 2, cidx1 = wid * 2 + 1;
  int rA0 = cidx0 * 16 + (lane >> 2), rA1 = cidx1 * 16 + (lane >> 2);
  int chm = ((lane & 3) ^ ((lane >> 2) & 3)) * 8;
  const u16* Asrc0 = Ag + (size_t)rA0 * 1024 + chm;
  const u16* Asrc1 = Ag + (size_t)rA1 * 1024 + chm;
  const u16* Bsrc0 = Bg + (size_t)rA0 * 1024 + chm;
  const u16* Bsrc1 = Bg + (size_t)rA1 * 1024 + chm;
  u16* lA0 = As + cidx0 * 512; u16* lA1 = As + cidx1 * 512;
  u16* lB0 = Bs + cidx0 * 512; u16* lB1 = Bs + cidx1 * 512;
  int aoff[4], boff[4];
#pragma unroll
  for (int i = 0; i < 4; ++i) {
    aoff[i] = (wm + i * 16 + lr) * 64 + ((lg * 16) ^ ((lr & 3) << 4));
    boff[i] = (wn + i * 16 + lr) * 64 + ((lg * 16) ^ ((lr & 3) << 4));
  }
  fx4 acc[4][4] = {};
  for (int kt = 0; kt < 32; ++kt) {
    __syncthreads();
    gload16(Asrc0 + kt * 32, lA0);
    gload16(Asrc1 + kt * 32, lA1);
    gload16(Bsrc0 + kt * 32, lB0);
    gload16(Bsrc1 + kt * 32, lB1);
    __syncthreads();
    frag8 af[4], bf_[4];
#pragma unroll
    for (int i = 0; i < 4; ++i) af[i] = *(const frag8*)((const char*)As + aoff[i]);
#pragma unroll
    for (int i = 0; i < 4; ++i) bf_[i] = *(const frag8*)((const char*)Bs + boff[i]);
#pragma unroll
    for (int mi = 0; mi < 4; ++mi)
#pragma unroll
      for (int ni = 0; ni < 4; ++ni) acc[mi][ni] = MFMA(af[mi], bf_[ni], acc[mi][ni]);
  }
#pragma unroll
  for (int mi = 0; mi < 4; ++mi)
#pragma unroll
    for (int r = 0; r < 4; ++r) {
      int m = m0 + wm + mi * 16 + lg * 4 + r;
      if (MODE == 0) {
        int b = m >> 11, t = m & 2047;
#pragma unroll
        for (int ni = 0; ni < 4; ++ni) {
          int n = n0 + wn + ni * 16 + lr;
          int type = n >> 10, h = (n >> 6) & 15, d = n & 63;
          u16* dst = (type == 0) ? Qb : ((type == 1) ? Kb : Vb);
          dst[((size_t)(b * 16 + h) * 2048 + t) * 64 + d] = f2bf(acc[mi][ni][r]);
        }
      } else {
#pragma unroll
        for (int ni = 0; ni < 4; ++ni) {
          int n = n0 + wn + ni * 16 + lr;
          outp[(size_t)m * 1024 + n] = acc[mi][ni][r] + bp[n];
        }
      }
    }
}

// ---------------- flash attention (swapped QK^T, in-register softmax) ----------------
// grid (bh=64, 32); qt = 31 - by for load balance. 4 waves x 16 q-rows, KV tile 64.

__global__ __launch_bounds__(256) void attn(const u16* __restrict__ Qb, const u16* __restrict__ Kb,
                                            const u16* __restrict__ VTg, u16* __restrict__ Ao,
                                            const int* __restrict__ mflag) {
  __shared__ u16 Ks[64 * 64];  // [s][d] swizzled
  __shared__ u16 Vs[64 * 64];  // [d][s] swizzled (from pre-transposed V)
  int tid = threadIdx.x, wid = tid >> 6, lane = tid & 63, lr = lane & 15, lg = lane >> 4;
  int bh = blockIdx.x;
  int qt = 31 - (int)blockIdx.y;
  int masked = mflag[0];
  int qbase = qt * 64;
  const u16* Qh = Qb + (size_t)bh * (2048 * 64);
  const u16* Kh = Kb + (size_t)bh * (2048 * 64);
  const u16* Vh = VTg + (size_t)bh * (64 * 2048);
  int qrow = qbase + wid * 16 + lr;
  frag8 qf0 = *(const frag8*)(Qh + (size_t)qrow * 64 + lg * 8);
  frag8 qf1 = *(const frag8*)(Qh + (size_t)qrow * 64 + 32 + lg * 8);
  float m_run = -__builtin_inff(), l_run = 0.f;
  fx4 oacc[4] = {};
  // gload staging: 8 rows per call; chunk = (lane&7)^(lane>>3)
  int cidx0 = wid * 2, cidx1 = wid * 2 + 1;
  int rr = lane >> 3, cc8 = ((lane & 7) ^ rr) * 8;
  int krow0 = cidx0 * 8 + rr, krow1 = cidx1 * 8 + rr;
  const u16* kp0 = Kh + (size_t)krow0 * 64 + cc8;
  const u16* kp1 = Kh + (size_t)krow1 * 64 + cc8;
  const u16* vp0 = Vh + (size_t)krow0 * 2048 + cc8;
  const u16* vp1 = Vh + (size_t)krow1 * 2048 + cc8;
  u16* lK0 = Ks + cidx0 * 512; u16* lK1 = Ks + cidx1 * 512;
  u16* lV0 = Vs + cidx0 * 512; u16* lV1 = Vs + cidx1 * 512;
  int ntiles = masked ? (qt + 1) : 32;
  for (int kt = 0; kt < ntiles; ++kt) {
    int s0 = kt * 64;
    __syncthreads();
    gload16(kp0 + (size_t)s0 * 64, lK0);
    gload16(kp1 + (size_t)s0 * 64, lK1);
    gload16(vp0 + s0, lV0);
    gload16(vp1 + s0, lV1);
    __syncthreads();
    // S^T = K * Q^T : lane holds S[q=lr][s = s0 + nt*16 + lg*4 + r]
    fx4 sc[4];
#pragma unroll
    for (int nt = 0; nt < 4; ++nt) {
      int row = nt * 16 + lr, swz = (row & 7) << 4;
      frag8 ka = *(const frag8*)((const char*)Ks + row * 128 + ((lg * 16) ^ swz));
      frag8 kb = *(const frag8*)((const char*)Ks + row * 128 + ((64 + lg * 16) ^ swz));
      fx4 a = {};
      a = MFMA(ka, qf0, a);
      a = MFMA(kb, qf1, a);
      sc[nt] = a;
    }
#pragma unroll
    for (int nt = 0; nt < 4; ++nt)
#pragma unroll
      for (int r = 0; r < 4; ++r) sc[nt][r] *= 0.03125f;  // 1/sqrt(1024)
    if (masked && kt == qt) {
      int q_l = wid * 16 + lr;
#pragma unroll
      for (int nt = 0; nt < 4; ++nt)
#pragma unroll
        for (int r = 0; r < 4; ++r)
          if (nt * 16 + lg * 4 + r > q_l) sc[nt][r] = -__builtin_inff();
    }
    // online softmax: full row = this lane's 16 values + xor16/xor32 partners
    float mx = sc[0][0];
#pragma unroll
    for (int nt = 0; nt < 4; ++nt)
#pragma unroll
      for (int r = 0; r < 4; ++r) mx = fmaxf(mx, sc[nt][r]);
    mx = fmaxf(mx, __shfl_xor(mx, 16));
    mx = fmaxf(mx, __shfl_xor(mx, 32));
    float mn = fmaxf(m_run, mx);
    float ps = 0.f;
#pragma unroll
    for (int nt = 0; nt < 4; ++nt)
#pragma unroll
      for (int r = 0; r < 4; ++r) {
        float p = __expf(sc[nt][r] - mn);
        sc[nt][r] = p;
        ps += p;
      }
    ps += __shfl_xor(ps, 16);
    ps += __shfl_xor(ps, 32);
    float al = __expf(m_run - mn);
    m_run = mn;
    l_run = l_run * al + ps;
    float alr[4];
#pragma unroll
    for (int r = 0; r < 4; ++r) alr[r] = __shfl(al, lg * 4 + r);
#pragma unroll
    for (int dt = 0; dt < 4; ++dt)
#pragma unroll
      for (int r = 0; r < 4; ++r) oacc[dt][r] *= alr[r];
    // pack P rows into PV A-fragments in-register
    u32 pw[4][2];
#pragma unroll
    for (int nt = 0; nt < 4; ++nt) {
      pw[nt][0] = cvtpk(sc[nt][0], sc[nt][1]);
      pw[nt][1] = cvtpk(sc[nt][2], sc[nt][3]);
    }
    int srcA = ((lg & 1) * 2) * 16 + lr;
    int srcB = srcA + 16;
    bool hisel = (lg >> 1) != 0;
    union { u32x4 u; frag8 f; } P0, P1;
#pragma unroll
    for (int w = 0; w < 4; ++w) {
      int src = (w < 2) ? srcA : srcB;
      int h = w & 1;
      u32 a0 = (u32)__shfl((int)pw[0][h], src);
      u32 a1 = (u32)__shfl((int)pw[1][h], src);
      P0.u[w] = hisel ? a1 : a0;
      u32 b0 = (u32)__shfl((int)pw[2][h], src);
      u32 b1 = (u32)__shfl((int)pw[3][h], src);
      P1.u[w] = hisel ? b1 : b0;
    }
    // O += P * V
#pragma unroll
    for (int dt = 0; dt < 4; ++dt) {
      int row = dt * 16 + lr, swz = (row & 7) << 4;
      frag8 vf0 = *(const frag8*)((const char*)Vs + row * 128 + ((lg * 16) ^ swz));
      frag8 vf1 = *(const frag8*)((const char*)Vs + row * 128 + ((64 + lg * 16) ^ swz));
      oacc[dt] = MFMA(P0.f, vf0, oacc[dt]);
      oacc[dt] = MFMA(P1.f, vf1, oacc[dt]);
    }
  }
  float inv = 1.0f / l_run;
  float invr[4];
#pragma unroll
  for (int r = 0; r < 4; ++r) invr[r] = __shfl(inv, lg * 4 + r);
  int b = bh >> 4, h = bh & 15;
#pragma unroll
  for (int r = 0; r < 4; ++r) {
    int rowg = qbase + wid * 16 + lg * 4 + r;
    size_t base = ((size_t)b * 2048 + rowg) * 1024 + h * 64;
#pragma unroll
    for (int dt = 0; dt < 4; ++dt) Ao[base + dt * 16 + lr] = f2bf(oacc[dt][r] * invr[r]);
  }
}

// ---------------- launch ----------------

extern "C" void kernel_launch(void* const* d_in, const int* in_sizes, int n_in,
                              void* d_out, int out_size, void* d_ws, size_t ws_size,
                              hipStream_t stream) {
  const float* x = (const float*)d_in[0];
  const float* Wq = (const float*)d_in[1];
  const float* Wk = (const float*)d_in[2];
  const float* Wv = (const float*)d_in[3];
  const float* Wp = (const float*)d_in[4];
  const float* bp = (const float*)d_in[5];
  const int* is_masked = (const int*)d_in[6];
  float* out = (float*)d_out;
  char* ws = (char*)d_ws;
  u16* Xbf = (u16*)(ws + 0);              // 16 MB (reused as VT after gemm<0>)
  u16* Wt  = (u16*)(ws + 16777216);       // 6 MB
  u16* Wpb = (u16*)(ws + 23068672);       // 2 MB
  u16* Qb  = (u16*)(ws + 25165824);       // 16 MB
  u16* Kb  = (u16*)(ws + 41943040);       // 16 MB
  u16* Vb  = (u16*)(ws + 58720256);       // 16 MB
  u16* Ao  = (u16*)(ws + 75497472);       // 16 MB
  u16* VTg = Xbf;                         // alias: Xbf dead after gemm<0>

  cvt_x<<<2048, 256, 0, stream>>>(x, Xbf);
  cvt_wqkv<<<dim3(48, 16), 256, 0, stream>>>(Wq, Wk, Wv, Wt);
  cvt_wp<<<1024, 256, 0, stream>>>(Wp, Wpb);
  gemm_bt<0><<<dim3(64, 24), 256, 0, stream>>>(Xbf, Wt, Qb, Kb, Vb, nullptr, nullptr);
  transpose_v<<<dim3(64, 32), 256, 0, stream>>>(Vb, VTg);
  attn<<<dim3(64, 32), 256, 0, stream>>>(Qb, Kb, VTg, Ao, is_masked);
  gemm_bt<1><<<dim3(64, 8), 256, 0, stream>>>(Ao, Wpb, nullptr, nullptr, nullptr, out, bp);
}

// Round 3
// 168.725 us; speedup vs baseline: 2.0110x; 1.1690x over previous
//
#include <hip/hip_runtime.h>
#include <stdint.h>
#include <type_traits>

typedef unsigned short u16;
typedef unsigned int u32;
typedef __attribute__((ext_vector_type(8))) short frag8;   // 8 bf16 (4 VGPRs)
typedef __attribute__((ext_vector_type(4))) float fx4;     // 4 fp32 acc
typedef __attribute__((ext_vector_type(16))) float fx16;   // 16 fp32 acc (32x32)

#define MFMA(a, b, c) __builtin_amdgcn_mfma_f32_16x16x32_bf16((a), (b), (c), 0, 0, 0)
#define MFMA32(a, b, c) __builtin_amdgcn_mfma_f32_32x32x16_bf16((a), (b), (c), 0, 0, 0)

__device__ __forceinline__ void gload16(const void* g, void* l) {
  __builtin_amdgcn_global_load_lds((const __attribute__((address_space(1))) void*)g,
                                   (__attribute__((address_space(3))) void*)l, 16, 0, 0);
}

__device__ __forceinline__ u16 f2bf(float f) {
  union { float f; unsigned int u; } c; c.f = f;
  unsigned int r = c.u + 0x7FFFu + ((c.u >> 16) & 1u);  // RNE
  return (u16)(r >> 16);
}

__device__ __forceinline__ u32 cvtpk(float lo, float hi) {
  u32 r;
  asm("v_cvt_pk_bf16_f32 %0, %1, %2" : "=v"(r) : "v"(lo), "v"(hi));
  return r;
}

// ---------------- conversions ----------------

__global__ __launch_bounds__(256) void cvt_x(const float* __restrict__ x, u16* __restrict__ xb) {
  const int n4 = (8192 * 1024) / 4;
  for (int i = blockIdx.x * 256 + threadIdx.x; i < n4; i += 2048 * 256) {
    float4 v = ((const float4*)x)[i];
    ushort4 o;
    o.x = f2bf(v.x); o.y = f2bf(v.y); o.z = f2bf(v.z); o.w = f2bf(v.w);
    ((ushort4*)xb)[i] = o;
  }
}

// Wq/Wk/Wv [H][C][D] -> Wt [(type*16+h)*64+d][c]  (N=3072 rows, K=1024)
__global__ __launch_bounds__(256) void cvt_wqkv(const float* __restrict__ Wq,
                                                const float* __restrict__ Wk,
                                                const float* __restrict__ Wv,
                                                u16* __restrict__ Wt) {
  __shared__ u16 Tls[64][72];  // +pad
  int hh = blockIdx.x;            // 0..47
  int c0 = blockIdx.y * 64;
  int type = hh >> 4, h = hh & 15;
  const float* Wsrc = (type == 0 ? Wq : (type == 1 ? Wk : Wv)) + (size_t)h * 1024 * 64;
  int t = threadIdx.x;
  int cr = t >> 4, q4 = (t & 15) * 4;
  for (int i = 0; i < 4; ++i) {
    int c = cr + i * 16;
    float4 v = *(const float4*)(Wsrc + (size_t)(c0 + c) * 64 + q4);
    Tls[q4 + 0][c] = f2bf(v.x);
    Tls[q4 + 1][c] = f2bf(v.y);
    Tls[q4 + 2][c] = f2bf(v.z);
    Tls[q4 + 3][c] = f2bf(v.w);
  }
  __syncthreads();
  for (int i = 0; i < 4; ++i) {
    int d = cr + i * 16;
    ushort4 o;
    o.x = Tls[d][q4 + 0]; o.y = Tls[d][q4 + 1]; o.z = Tls[d][q4 + 2]; o.w = Tls[d][q4 + 3];
    *(ushort4*)(Wt + ((size_t)hh * 64 + d) * 1024 + c0 + q4) = o;
  }
}

__global__ __launch_bounds__(256) void cvt_wp(const float* __restrict__ Wp, u16* __restrict__ wb) {
  const int n4 = (1024 * 1024) / 4;
  for (int i = blockIdx.x * 256 + threadIdx.x; i < n4; i += 1024 * 256) {
    float4 v = ((const float4*)Wp)[i];
    ushort4 o;
    o.x = f2bf(v.x); o.y = f2bf(v.y); o.z = f2bf(v.z); o.w = f2bf(v.w);
    ((ushort4*)wb)[i] = o;
  }
}

// V [bh][2048][64] -> VT [bh][64][2048]
__global__ __launch_bounds__(256) void transpose_v(const u16* __restrict__ Vb, u16* __restrict__ VTg) {
  __shared__ u16 T[64 * 64];  // chunk-XOR swizzled rows of 128B
  int bh = blockIdx.x, t0 = blockIdx.y * 64;
  const u16* src = Vb + ((size_t)bh * 2048 + t0) * 64;
  int tid = threadIdx.x;
  int tl = tid >> 2, c16 = (tid & 3) * 16;
  int swzw = (tl & 7) << 4;
  frag8 a = *(const frag8*)(src + (size_t)tl * 64 + c16);
  frag8 b = *(const frag8*)(src + (size_t)tl * 64 + c16 + 8);
  *(frag8*)((char*)T + tl * 128 + ((c16 * 2) ^ swzw)) = a;
  *(frag8*)((char*)T + tl * 128 + ((c16 * 2 + 16) ^ swzw)) = b;
  __syncthreads();
  int d_ = tid & 63;
#pragma unroll
  for (int k = 0; k < 2; ++k) {
    int c_ = (tid >> 6) + 4 * k;
    frag8 o;
#pragma unroll
    for (int j = 0; j < 8; ++j) {
      int t = c_ * 8 + j;
      o[j] = *(const u16*)((const char*)T + t * 128 + ((2 * d_) ^ ((t & 7) << 4)));
    }
    *(frag8*)(VTg + ((size_t)bh * 64 + d_) * 2048 + t0 + c_ * 8) = o;
  }
}

// ---------------- GEMM: C[m][n] = sum_k A[m][k] * Bw[n][k], K=1024 ----------------

template <int MODE>
__global__ __launch_bounds__(256) void gemm_bt(const u16* __restrict__ A, const u16* __restrict__ Bw,
                                               u16* __restrict__ Qb, u16* __restrict__ Kb,
                                               u16* __restrict__ Vb, float* __restrict__ outp,
                                               const float* __restrict__ bp) {
  __shared__ u16 As[128 * 32];
  __shared__ u16 Bs[128 * 32];
  int tid = threadIdx.x;
  int m0 = blockIdx.x * 128, n0 = blockIdx.y * 128;
  int wid = tid >> 6, lane = tid & 63, lr = lane & 15, lg = lane >> 4;
  int wm = (wid >> 1) * 64, wn = (wid & 1) * 64;
  const u16* Ag = A + (size_t)m0 * 1024;
  const u16* Bg = Bw + (size_t)n0 * 1024;
  int cidx0 = wid * 2, cidx1 = wid * 2 + 1;
  int rA0 = cidx0 * 16 + (lane >> 2), rA1 = cidx1 * 16 + (lane >> 2);
  int chm = ((lane & 3) ^ ((lane >> 2) & 3)) * 8;
  const u16* Asrc0 = Ag + (size_t)rA0 * 1024 + chm;
  const u16* Asrc1 = Ag + (size_t)rA1 * 1024 + chm;
  const u16* Bsrc0 = Bg + (size_t)rA0 * 1024 + chm;
  const u16* Bsrc1 = Bg + (size_t)rA1 * 1024 + chm;
  u16* lA0 = As + cidx0 * 512; u16* lA1 = As + cidx1 * 512;
  u16* lB0 = Bs + cidx0 * 512; u16* lB1 = Bs + cidx1 * 512;
  int aoff[4], boff[4];
#pragma unroll
  for (int i = 0; i < 4; ++i) {
    aoff[i] = (wm + i * 16 + lr) * 64 + ((lg * 16) ^ ((lr & 3) << 4));
    boff[i] = (wn + i * 16 + lr) * 64 + ((lg * 16) ^ ((lr & 3) << 4));
  }
  fx4 acc[4][4] = {};
  for (int kt = 0; kt < 32; ++kt) {
    __syncthreads();
    gload16(Asrc0 + kt * 32, lA0);
    gload16(Asrc1 + kt * 32, lA1);
    gload16(Bsrc0 + kt * 32, lB0);
    gload16(Bsrc1 + kt * 32, lB1);
    __syncthreads();
    frag8 af[4], bf_[4];
#pragma unroll
    for (int i = 0; i < 4; ++i) af[i] = *(const frag8*)((const char*)As + aoff[i]);
#pragma unroll
    for (int i = 0; i < 4; ++i) bf_[i] = *(const frag8*)((const char*)Bs + boff[i]);
#pragma unroll
    for (int mi = 0; mi < 4; ++mi)
#pragma unroll
      for (int ni = 0; ni < 4; ++ni) acc[mi][ni] = MFMA(af[mi], bf_[ni], acc[mi][ni]);
  }
#pragma unroll
  for (int mi = 0; mi < 4; ++mi)
#pragma unroll
    for (int r = 0; r < 4; ++r) {
      int m = m0 + wm + mi * 16 + lg * 4 + r;
      if (MODE == 0) {
        int b = m >> 11, t = m & 2047;
#pragma unroll
        for (int ni = 0; ni < 4; ++ni) {
          int n = n0 + wn + ni * 16 + lr;
          int type = n >> 10, h = (n >> 6) & 15, d = n & 63;
          u16* dst = (type == 0) ? Qb : ((type == 1) ? Kb : Vb);
          float v = acc[mi][ni][r];
          if (type == 0) v *= 0.04508422002778011f;  // log2(e)/32 folded into Q
          dst[((size_t)(b * 16 + h) * 2048 + t) * 64 + d] = f2bf(v);
        }
      } else {
#pragma unroll
        for (int ni = 0; ni < 4; ++ni) {
          int n = n0 + wn + ni * 16 + lr;
          outp[(size_t)m * 1024 + n] = acc[mi][ni][r] + bp[n];
        }
      }
    }
}

// ---------------- flash attention: 32x32 MFMA, q in lane&31, 2-phase pipeline ----------------
// grid (bh=64, 16); block = 128 q-rows, 4 waves x 32 q. KV tile 64, double-buffered.

__global__ __launch_bounds__(256, 4) void attn(const u16* __restrict__ Qb, const u16* __restrict__ Kb,
                                               const u16* __restrict__ VTg, u16* __restrict__ Ao,
                                               const int* __restrict__ mflag) {
  // LDS map (bytes): K buf0 @0, K buf1 @8192, V buf0 @16384, V buf1 @24576
  __shared__ __align__(16) char LDS[32768];
  const int tid = threadIdx.x, w = tid >> 6, lane = tid & 63;
  const int l31 = lane & 31, hi = lane >> 5;
  const int bh = blockIdx.x;
  const int qt = 15 - (int)blockIdx.y;   // big blocks first
  const int masked = mflag[0];
  const int qbase = qt * 128;
  const u16* Qh = Qb + (size_t)bh * (2048 * 64);
  const u16* Kh = Kb + (size_t)bh * (2048 * 64);
  const u16* Vh = VTg + (size_t)bh * (64 * 2048);
  const int qrow = qbase + w * 32 + l31;
  frag8 qf[4];
#pragma unroll
  for (int s = 0; s < 4; ++s) qf[s] = *(const frag8*)(Qh + (size_t)qrow * 64 + s * 16 + hi * 8);
  // staging (global_load_lds): call c covers rows c*8..c*8+7; lane chunk pre-swizzled
  const int srow = lane >> 3;
  const int schunk = ((lane & 7) ^ srow) * 8;
  const int c0 = w * 2, c1 = w * 2 + 1;
  const u16* kg0 = Kh + (size_t)(c0 * 8 + srow) * 64 + schunk;
  const u16* kg1 = Kh + (size_t)(c1 * 8 + srow) * 64 + schunk;
  const u16* vg0 = Vh + (size_t)(c0 * 8 + srow) * 2048 + schunk;
  const u16* vg1 = Vh + (size_t)(c1 * 8 + srow) * 2048 + schunk;
  // LDS read base (byte): row l31 (+slab*4096), chunk XOR swizzle
  const int aK = l31 * 128 + ((hi * 16) ^ ((l31 & 7) << 4));
  const int qmax_w = qbase + w * 32 + 31;
  const int qmin_w = qbase + w * 32;
  float m_run = -__builtin_inff(), l_run = 0.f;
  fx16 oa0 = {}, oa1 = {};
  const int nt = masked ? (2 * qt + 2) : 32;

  auto STAGE = [&](int B, int T) {
    size_t ko = (size_t)T * 4096, vo = (size_t)T * 64;
    gload16(kg0 + ko, LDS + B * 8192 + c0 * 1024);
    gload16(kg1 + ko, LDS + B * 8192 + c1 * 1024);
    gload16(vg0 + vo, LDS + 16384 + B * 8192 + c0 * 1024);
    gload16(vg1 + vo, LDS + 16384 + B * 8192 + c1 * 1024);
  };

  auto TILE = [&](auto Bc, int T) {
    constexpr int B = decltype(Bc)::value;
    if (T + 1 < nt) STAGE(B ^ 1, T + 1);
    bool act = (!masked) || (T * 64 <= qmax_w);
    if (act) {
      // ---- S^T = K * Q^T (64s x 32q) ----
      fx16 s0v = {}, s1v = {};
#pragma unroll
      for (int ds = 0; ds < 4; ++ds) {
        frag8 k0 = *(const frag8*)(LDS + B * 8192 + (aK ^ (ds << 5)));
        frag8 k1 = *(const frag8*)(LDS + B * 8192 + 4096 + (aK ^ (ds << 5)));
        s0v = MFMA32(k0, qf[ds], s0v);
        s1v = MFMA32(k1, qf[ds], s1v);
      }
      // ---- causal mask (diagonal tiles only) ----
      if (masked && T * 64 + 63 > qmin_w) {
#pragma unroll
        for (int g = 0; g < 4; ++g)
#pragma unroll
          for (int r = 0; r < 4; ++r) {
            int sg = T * 64 + r + 8 * g + 4 * hi;
            if (sg > qrow) s0v[4 * g + r] = -__builtin_inff();
            if (sg + 32 > qrow) s1v[4 * g + r] = -__builtin_inff();
          }
      }
      // ---- online softmax (row q = l31, partner = lane^32) ----
      float mx = s0v[0];
#pragma unroll
      for (int i = 1; i < 16; ++i) mx = fmaxf(mx, s0v[i]);
#pragma unroll
      for (int i = 0; i < 16; ++i) mx = fmaxf(mx, s1v[i]);
      mx = fmaxf(mx, __int_as_float(__shfl_xor(__float_as_int(mx), 32)));
      if (!__all(mx <= m_run + 8.0f)) {   // defer-max (T13)
        float mn = fmaxf(m_run, mx);
        float al = __builtin_amdgcn_exp2f(m_run - mn);
#pragma unroll
        for (int i = 0; i < 16; ++i) { oa0[i] *= al; oa1[i] *= al; }
        l_run *= al;
        m_run = mn;
      }
      float ps = 0.f;
#pragma unroll
      for (int i = 0; i < 16; ++i) {
        s0v[i] = __builtin_amdgcn_exp2f(s0v[i] - m_run); ps += s0v[i];
      }
#pragma unroll
      for (int i = 0; i < 16; ++i) {
        s1v[i] = __builtin_amdgcn_exp2f(s1v[i] - m_run); ps += s1v[i];
      }
      ps += __int_as_float(__shfl_xor(__float_as_int(ps), 32));
      l_run += ps;
      // ---- O^T += V^T * P  (4 k-tiles of 16 s) ----
#pragma unroll
      for (int kt = 0; kt < 4; ++kt) {
        const int b8 = (kt & 1) * 8;
        float p0, p1, p2, p3, p4, p5, p6, p7;
        if (kt < 2) { p0=s0v[b8+0];p1=s0v[b8+1];p2=s0v[b8+2];p3=s0v[b8+3];p4=s0v[b8+4];p5=s0v[b8+5];p6=s0v[b8+6];p7=s0v[b8+7]; }
        else        { p0=s1v[b8+0];p1=s1v[b8+1];p2=s1v[b8+2];p3=s1v[b8+3];p4=s1v[b8+4];p5=s1v[b8+5];p6=s1v[b8+6];p7=s1v[b8+7]; }
        u32 X0 = cvtpk(p0, p1), X1 = cvtpk(p2, p3);
        u32 Y0 = cvtpk(p4, p5), Y1 = cvtpk(p6, p7);
        u32 sel0 = hi ? X0 : Y0, sel1 = hi ? X1 : Y1;
        u32 got0 = (u32)__shfl_xor((int)sel0, 32);
        u32 got1 = (u32)__shfl_xor((int)sel1, 32);
        union { u32 u[4]; frag8 f; } pf;
        pf.u[0] = hi ? got0 : X0;
        pf.u[1] = hi ? got1 : X1;
        pf.u[2] = hi ? Y0 : got0;
        pf.u[3] = hi ? Y1 : got1;
        frag8 v0 = *(const frag8*)(LDS + 16384 + B * 8192 + (aK ^ (kt << 5)));
        frag8 v1 = *(const frag8*)(LDS + 16384 + B * 8192 + 4096 + (aK ^ (kt << 5)));
        oa0 = MFMA32(v0, pf.f, oa0);
        oa1 = MFMA32(v1, pf.f, oa1);
      }
    }
    asm volatile("s_waitcnt vmcnt(0)" ::: "memory");
    __builtin_amdgcn_s_barrier();
  };

  STAGE(0, 0);
  asm volatile("s_waitcnt vmcnt(0)" ::: "memory");
  __builtin_amdgcn_s_barrier();
  int t = 0;
  while (true) {
    TILE(std::integral_constant<int, 0>{}, t); ++t; if (t >= nt) break;
    TILE(std::integral_constant<int, 1>{}, t); ++t; if (t >= nt) break;
  }

  // ---- epilogue: normalize + write O[q][d] ----
  float inv = 1.0f / l_run;
  int b = bh >> 4, hh = bh & 15;
  u16* orow = Ao + ((size_t)b * 2048 + qrow) * 1024 + hh * 64;
#pragma unroll
  for (int g = 0; g < 4; ++g) {
    int d0 = 8 * g + 4 * hi;
    u32 wA = cvtpk(oa0[4 * g + 0] * inv, oa0[4 * g + 1] * inv);
    u32 wB = cvtpk(oa0[4 * g + 2] * inv, oa0[4 * g + 3] * inv);
    u32 wC = cvtpk(oa1[4 * g + 0] * inv, oa1[4 * g + 1] * inv);
    u32 wD = cvtpk(oa1[4 * g + 2] * inv, oa1[4 * g + 3] * inv);
    *(u32*)(orow + d0 + 0) = wA;
    *(u32*)(orow + d0 + 2) = wB;
    *(u32*)(orow + d0 + 32) = wC;
    *(u32*)(orow + d0 + 34) = wD;
  }
}

// ---------------- launch ----------------

extern "C" void kernel_launch(void* const* d_in, const int* in_sizes, int n_in,
                              void* d_out, int out_size, void* d_ws, size_t ws_size,
                              hipStream_t stream) {
  const float* x = (const float*)d_in[0];
  const float* Wq = (const float*)d_in[1];
  const float* Wk = (const float*)d_in[2];
  const float* Wv = (const float*)d_in[3];
  const float* Wp = (const float*)d_in[4];
  const float* bp = (const float*)d_in[5];
  const int* is_masked = (const int*)d_in[6];
  float* out = (float*)d_out;
  char* ws = (char*)d_ws;
  u16* Xbf = (u16*)(ws + 0);              // 16 MB (reused as VT after gemm<0>)
  u16* Wt  = (u16*)(ws + 16777216);       // 6 MB
  u16* Wpb = (u16*)(ws + 23068672);       // 2 MB
  u16* Qb  = (u16*)(ws + 25165824);       // 16 MB
  u16* Kb  = (u16*)(ws + 41943040);       // 16 MB
  u16* Vb  = (u16*)(ws + 58720256);       // 16 MB
  u16* Ao  = (u16*)(ws + 75497472);       // 16 MB
  u16* VTg = Xbf;                         // alias: Xbf dead after gemm<0>

  cvt_x<<<2048, 256, 0, stream>>>(x, Xbf);
  cvt_wqkv<<<dim3(48, 16), 256, 0, stream>>>(Wq, Wk, Wv, Wt);
  cvt_wp<<<1024, 256, 0, stream>>>(Wp, Wpb);
  gemm_bt<0><<<dim3(64, 24), 256, 0, stream>>>(Xbf, Wt, Qb, Kb, Vb, nullptr, nullptr);
  transpose_v<<<dim3(64, 32), 256, 0, stream>>>(Vb, VTg);
  attn<<<dim3(64, 16), 256, 0, stream>>>(Qb, Kb, VTg, Ao, is_masked);
  gemm_bt<1><<<dim3(64, 8), 256, 0, stream>>>(Ao, Wpb, nullptr, nullptr, nullptr, out, bp);
}

// Round 4
// 166.557 us; speedup vs baseline: 2.0372x; 1.0130x over previous
//
#include <hip/hip_runtime.h>
#include <stdint.h>
#include <type_traits>

typedef unsigned short u16;
typedef unsigned int u32;
typedef __attribute__((ext_vector_type(8))) short frag8;   // 8 bf16 (4 VGPRs)
typedef __attribute__((ext_vector_type(4))) float fx4;     // 4 fp32 acc
typedef __attribute__((ext_vector_type(16))) float fx16;   // 16 fp32 acc (32x32)

#define MFMA(a, b, c) __builtin_amdgcn_mfma_f32_16x16x32_bf16((a), (b), (c), 0, 0, 0)
#define MFMA32(a, b, c) __builtin_amdgcn_mfma_f32_32x32x16_bf16((a), (b), (c), 0, 0, 0)

__device__ __forceinline__ void gload16(const void* g, void* l) {
  __builtin_amdgcn_global_load_lds((const __attribute__((address_space(1))) void*)g,
                                   (__attribute__((address_space(3))) void*)l, 16, 0, 0);
}

__device__ __forceinline__ u16 f2bf(float f) {
  union { float f; unsigned int u; } c; c.f = f;
  unsigned int r = c.u + 0x7FFFu + ((c.u >> 16) & 1u);  // RNE
  return (u16)(r >> 16);
}

__device__ __forceinline__ u32 cvtpk(float lo, float hi) {
  u32 r;
  asm("v_cvt_pk_bf16_f32 %0, %1, %2" : "=v"(r) : "v"(lo), "v"(hi));
  return r;
}

// ---------------- conversions ----------------

__global__ __launch_bounds__(256) void cvt_x(const float* __restrict__ x, u16* __restrict__ xb) {
  const int n4 = (8192 * 1024) / 4;
  for (int i = blockIdx.x * 256 + threadIdx.x; i < n4; i += 2048 * 256) {
    float4 v = ((const float4*)x)[i];
    ushort4 o;
    o.x = f2bf(v.x); o.y = f2bf(v.y); o.z = f2bf(v.z); o.w = f2bf(v.w);
    ((ushort4*)xb)[i] = o;
  }
}

// Wq/Wk/Wv [H][C][D] -> Wt [(type*16+h)*64+d][c]  (N=3072 rows, K=1024)
__global__ __launch_bounds__(256) void cvt_wqkv(const float* __restrict__ Wq,
                                                const float* __restrict__ Wk,
                                                const float* __restrict__ Wv,
                                                u16* __restrict__ Wt) {
  __shared__ u16 Tls[64][72];  // +pad
  int hh = blockIdx.x;            // 0..47
  int c0 = blockIdx.y * 64;
  int type = hh >> 4, h = hh & 15;
  const float* Wsrc = (type == 0 ? Wq : (type == 1 ? Wk : Wv)) + (size_t)h * 1024 * 64;
  int t = threadIdx.x;
  int cr = t >> 4, q4 = (t & 15) * 4;
  for (int i = 0; i < 4; ++i) {
    int c = cr + i * 16;
    float4 v = *(const float4*)(Wsrc + (size_t)(c0 + c) * 64 + q4);
    Tls[q4 + 0][c] = f2bf(v.x);
    Tls[q4 + 1][c] = f2bf(v.y);
    Tls[q4 + 2][c] = f2bf(v.z);
    Tls[q4 + 3][c] = f2bf(v.w);
  }
  __syncthreads();
  for (int i = 0; i < 4; ++i) {
    int d = cr + i * 16;
    ushort4 o;
    o.x = Tls[d][q4 + 0]; o.y = Tls[d][q4 + 1]; o.z = Tls[d][q4 + 2]; o.w = Tls[d][q4 + 3];
    *(ushort4*)(Wt + ((size_t)hh * 64 + d) * 1024 + c0 + q4) = o;
  }
}

__global__ __launch_bounds__(256) void cvt_wp(const float* __restrict__ Wp, u16* __restrict__ wb) {
  const int n4 = (1024 * 1024) / 4;
  for (int i = blockIdx.x * 256 + threadIdx.x; i < n4; i += 1024 * 256) {
    float4 v = ((const float4*)Wp)[i];
    ushort4 o;
    o.x = f2bf(v.x); o.y = f2bf(v.y); o.z = f2bf(v.z); o.w = f2bf(v.w);
    ((ushort4*)wb)[i] = o;
  }
}

// V [bh][2048][64] -> VT [bh][64][2048]
__global__ __launch_bounds__(256) void transpose_v(const u16* __restrict__ Vb, u16* __restrict__ VTg) {
  __shared__ u16 T[64 * 64];  // chunk-XOR swizzled rows of 128B
  int bh = blockIdx.x, t0 = blockIdx.y * 64;
  const u16* src = Vb + ((size_t)bh * 2048 + t0) * 64;
  int tid = threadIdx.x;
  int tl = tid >> 2, c16 = (tid & 3) * 16;
  int swzw = (tl & 7) << 4;
  frag8 a = *(const frag8*)(src + (size_t)tl * 64 + c16);
  frag8 b = *(const frag8*)(src + (size_t)tl * 64 + c16 + 8);
  *(frag8*)((char*)T + tl * 128 + ((c16 * 2) ^ swzw)) = a;
  *(frag8*)((char*)T + tl * 128 + ((c16 * 2 + 16) ^ swzw)) = b;
  __syncthreads();
  int d_ = tid & 63;
#pragma unroll
  for (int k = 0; k < 2; ++k) {
    int c_ = (tid >> 6) + 4 * k;
    frag8 o;
#pragma unroll
    for (int j = 0; j < 8; ++j) {
      int t = c_ * 8 + j;
      o[j] = *(const u16*)((const char*)T + t * 128 + ((2 * d_) ^ ((t & 7) << 4)));
    }
    *(frag8*)(VTg + ((size_t)bh * 64 + d_) * 2048 + t0 + c_ * 8) = o;
  }
}

// ---------------- QKV GEMM: 8-phase counted-vmcnt, BM=256 BN=192 BK=64, 512 thr ----------------
// C[m][n] = sum_k A[m][k]*Bw[n][k]; scatter bf16 to Q/K/V (Q scaled by log2e/32).

__global__ __launch_bounds__(512, 2) void gemm256(const u16* __restrict__ A, const u16* __restrict__ Bw,
                                                  u16* __restrict__ Qb, u16* __restrict__ Kb,
                                                  u16* __restrict__ Vb) {
  // LDS: A bufs @0/@32768 (256x64x2B each), B bufs @65536/@90112 (192x64x2B each)
  __shared__ __align__(16) char LDSC[114688];
  const int tid = threadIdx.x, w = tid >> 6, lane = tid & 63;
  const int lr = lane & 15, lg = lane >> 4;
  // XCD-chunked bijective swizzle over 512 blocks (32 m x 16 n)
  const int wg = blockIdx.x;
  const int xcd = wg & 7, loc = wg >> 3;
  const int bx = xcd * 4 + (loc >> 4);
  const int by = loc & 15;
  const int m0 = bx * 256, n0 = by * 192;
  // staging: line covers 64 rows; wave w rows [l*64+w*8, +8); inverse-swizzled source chunk
  const int r8 = lane >> 3;
  const int c8 = ((lane & 7) ^ r8) * 8;  // u16 offset
  const u16* aS[4]; const u16* bS[3];
  char* aD[4]; char* bD[3];
#pragma unroll
  for (int l = 0; l < 4; ++l) {
    aS[l] = A + (size_t)(m0 + l * 64 + w * 8 + r8) * 1024 + c8;
    aD[l] = LDSC + l * 8192 + w * 1024;
  }
#pragma unroll
  for (int l = 0; l < 3; ++l) {
    bS[l] = Bw + (size_t)(n0 + l * 64 + w * 8 + r8) * 1024 + c8;
    bD[l] = LDSC + 65536 + l * 8192 + w * 1024;
  }
  // LDS read addressing: row*128 bytes, col chunk (ks*4+lg)*16 XOR (lr&7)<<4
  const int colX0 = (lg << 4) ^ ((lr & 7) << 4);
  const int colX1 = ((4 + lg) << 4) ^ ((lr & 7) << 4);
  const int aRowB = ((w >> 2) * 128 + lr) * 128;
  const int bRowB = 65536 + ((w & 3) * 48 + lr) * 128;

  fx4 acc[8][3] = {};

  // prologue: stage tile 0, drain, barrier
#pragma unroll
  for (int l = 0; l < 4; ++l) gload16(aS[l], aD[l]);
#pragma unroll
  for (int l = 0; l < 3; ++l) gload16(bS[l], bD[l]);
  asm volatile("s_waitcnt vmcnt(0)" ::: "memory");
  __builtin_amdgcn_s_barrier();

  for (int kt = 0; kt < 16; ++kt) {
    const int ab = (kt & 1) * 32768;
    const int bb = (kt & 1) * 24576;
    frag8 bf2[3][2];
#pragma unroll
    for (int p = 0; p < 4; ++p) {
      if (p == 0) {
        if (kt + 1 < 16) {  // front-load next tile's staging (7 loads stay in flight)
          const int ko = (kt + 1) * 64;
          const int ab2 = ab ^ 32768, bb2 = bb ^ 24576;
#pragma unroll
          for (int l = 0; l < 4; ++l) gload16(aS[l] + ko, aD[l] + ab2);
#pragma unroll
          for (int l = 0; l < 3; ++l) gload16(bS[l] + ko, bD[l] + bb2);
        }
#pragma unroll
        for (int ni = 0; ni < 3; ++ni) {
          bf2[ni][0] = *(const frag8*)(LDSC + bb + bRowB + ni * 2048 + colX0);
          bf2[ni][1] = *(const frag8*)(LDSC + bb + bRowB + ni * 2048 + colX1);
        }
      }
      frag8 af2[2][2];
#pragma unroll
      for (int dm = 0; dm < 2; ++dm) {
        af2[dm][0] = *(const frag8*)(LDSC + ab + aRowB + (2 * p + dm) * 2048 + colX0);
        af2[dm][1] = *(const frag8*)(LDSC + ab + aRowB + (2 * p + dm) * 2048 + colX1);
      }
      __builtin_amdgcn_s_barrier();
      asm volatile("s_waitcnt lgkmcnt(0)" ::: "memory");
      __builtin_amdgcn_sched_barrier(0);
      __builtin_amdgcn_s_setprio(1);
#pragma unroll
      for (int dm = 0; dm < 2; ++dm)
#pragma unroll
        for (int ni = 0; ni < 3; ++ni)
#pragma unroll
          for (int ks = 0; ks < 2; ++ks)
            acc[2 * p + dm][ni] = MFMA(af2[dm][ks], bf2[ni][ks], acc[2 * p + dm][ni]);
      __builtin_amdgcn_s_setprio(0);
      __builtin_amdgcn_sched_barrier(0);
      if (p == 3) {
        asm volatile("s_waitcnt vmcnt(0)" ::: "memory");  // next tile landed (issued ~4 phases ago)
        __builtin_amdgcn_sched_barrier(0);
      }
      __builtin_amdgcn_s_barrier();
    }
  }

  // epilogue: scatter to Q/K/V
  const int wmB = (w >> 2) * 128, wnB = (w & 3) * 48;
#pragma unroll
  for (int mi = 0; mi < 8; ++mi)
#pragma unroll
    for (int r = 0; r < 4; ++r) {
      int m = m0 + wmB + mi * 16 + lg * 4 + r;
      int b = m >> 11, t = m & 2047;
#pragma unroll
      for (int ni = 0; ni < 3; ++ni) {
        int n = n0 + wnB + ni * 16 + lr;
        int type = n >> 10, h = (n >> 6) & 15, d = n & 63;
        u16* dst = (type == 0) ? Qb : ((type == 1) ? Kb : Vb);
        float v = acc[mi][ni][r];
        if (type == 0) v *= 0.04508422002778011f;  // log2(e)/32 folded into Q
        dst[((size_t)(b * 16 + h) * 2048 + t) * 64 + d] = f2bf(v);
      }
    }
}

// ---------------- proj GEMM (old 128x128 structure): C = A*Wp^T + bias, fp32 out ----------------

__global__ __launch_bounds__(256) void gemm_proj(const u16* __restrict__ A, const u16* __restrict__ Bw,
                                                 float* __restrict__ outp, const float* __restrict__ bp) {
  __shared__ u16 As[128 * 32];
  __shared__ u16 Bs[128 * 32];
  int tid = threadIdx.x;
  int m0 = blockIdx.x * 128, n0 = blockIdx.y * 128;
  int wid = tid >> 6, lane = tid & 63, lr = lane & 15, lg = lane >> 4;
  int wm = (wid >> 1) * 64, wn = (wid & 1) * 64;
  const u16* Ag = A + (size_t)m0 * 1024;
  const u16* Bg = Bw + (size_t)n0 * 1024;
  int cidx0 = wid * 2, cidx1 = wid * 2 + 1;
  int rA0 = cidx0 * 16 + (lane >> 2), rA1 = cidx1 * 16 + (lane >> 2);
  int chm = ((lane & 3) ^ ((lane >> 2) & 3)) * 8;
  const u16* Asrc0 = Ag + (size_t)rA0 * 1024 + chm;
  const u16* Asrc1 = Ag + (size_t)rA1 * 1024 + chm;
  const u16* Bsrc0 = Bg + (size_t)rA0 * 1024 + chm;
  const u16* Bsrc1 = Bg + (size_t)rA1 * 1024 + chm;
  u16* lA0 = As + cidx0 * 512; u16* lA1 = As + cidx1 * 512;
  u16* lB0 = Bs + cidx0 * 512; u16* lB1 = Bs + cidx1 * 512;
  int aoff[4], boff[4];
#pragma unroll
  for (int i = 0; i < 4; ++i) {
    aoff[i] = (wm + i * 16 + lr) * 64 + ((lg * 16) ^ ((lr & 3) << 4));
    boff[i] = (wn + i * 16 + lr) * 64 + ((lg * 16) ^ ((lr & 3) << 4));
  }
  fx4 acc[4][4] = {};
  for (int kt = 0; kt < 32; ++kt) {
    __syncthreads();
    gload16(Asrc0 + kt * 32, lA0);
    gload16(Asrc1 + kt * 32, lA1);
    gload16(Bsrc0 + kt * 32, lB0);
    gload16(Bsrc1 + kt * 32, lB1);
    __syncthreads();
    frag8 af[4], bf_[4];
#pragma unroll
    for (int i = 0; i < 4; ++i) af[i] = *(const frag8*)((const char*)As + aoff[i]);
#pragma unroll
    for (int i = 0; i < 4; ++i) bf_[i] = *(const frag8*)((const char*)Bs + boff[i]);
#pragma unroll
    for (int mi = 0; mi < 4; ++mi)
#pragma unroll
      for (int ni = 0; ni < 4; ++ni) acc[mi][ni] = MFMA(af[mi], bf_[ni], acc[mi][ni]);
  }
#pragma unroll
  for (int mi = 0; mi < 4; ++mi)
#pragma unroll
    for (int r = 0; r < 4; ++r) {
      int m = m0 + wm + mi * 16 + lg * 4 + r;
#pragma unroll
      for (int ni = 0; ni < 4; ++ni) {
        int n = n0 + wn + ni * 16 + lr;
        outp[(size_t)m * 1024 + n] = acc[mi][ni][r] + bp[n];
      }
    }
}

// ---------------- flash attention: 32x32 MFMA, q in lane&31, 2-phase pipeline ----------------
// grid (bh=64, 16); block = 128 q-rows, 4 waves x 32 q. KV tile 64, double-buffered.

__global__ __launch_bounds__(256, 4) void attn(const u16* __restrict__ Qb, const u16* __restrict__ Kb,
                                               const u16* __restrict__ VTg, u16* __restrict__ Ao,
                                               const int* __restrict__ mflag) {
  // LDS map (bytes): K buf0 @0, K buf1 @8192, V buf0 @16384, V buf1 @24576
  __shared__ __align__(16) char LDS[32768];
  const int tid = threadIdx.x, w = tid >> 6, lane = tid & 63;
  const int l31 = lane & 31, hi = lane >> 5;
  const int bh = blockIdx.x;
  const int qt = 15 - (int)blockIdx.y;   // big blocks first
  const int masked = mflag[0];
  const int qbase = qt * 128;
  const u16* Qh = Qb + (size_t)bh * (2048 * 64);
  const u16* Kh = Kb + (size_t)bh * (2048 * 64);
  const u16* Vh = VTg + (size_t)bh * (64 * 2048);
  const int qrow = qbase + w * 32 + l31;
  frag8 qf[4];
#pragma unroll
  for (int s = 0; s < 4; ++s) qf[s] = *(const frag8*)(Qh + (size_t)qrow * 64 + s * 16 + hi * 8);
  // staging (global_load_lds): call c covers rows c*8..c*8+7; lane chunk pre-swizzled
  const int srow = lane >> 3;
  const int schunk = ((lane & 7) ^ srow) * 8;
  const int c0 = w * 2, c1 = w * 2 + 1;
  const u16* kg0 = Kh + (size_t)(c0 * 8 + srow) * 64 + schunk;
  const u16* kg1 = Kh + (size_t)(c1 * 8 + srow) * 64 + schunk;
  const u16* vg0 = Vh + (size_t)(c0 * 8 + srow) * 2048 + schunk;
  const u16* vg1 = Vh + (size_t)(c1 * 8 + srow) * 2048 + schunk;
  // LDS read base (byte): row l31 (+slab*4096), chunk XOR swizzle
  const int aK = l31 * 128 + ((hi * 16) ^ ((l31 & 7) << 4));
  const int qmax_w = qbase + w * 32 + 31;
  const int qmin_w = qbase + w * 32;
  float m_run = -__builtin_inff(), l_run = 0.f;
  fx16 oa0 = {}, oa1 = {};
  const int nt = masked ? (2 * qt + 2) : 32;

  auto STAGE = [&](int B, int T) {
    size_t ko = (size_t)T * 4096, vo = (size_t)T * 64;
    gload16(kg0 + ko, LDS + B * 8192 + c0 * 1024);
    gload16(kg1 + ko, LDS + B * 8192 + c1 * 1024);
    gload16(vg0 + vo, LDS + 16384 + B * 8192 + c0 * 1024);
    gload16(vg1 + vo, LDS + 16384 + B * 8192 + c1 * 1024);
  };

  auto TILE = [&](auto Bc, int T) {
    constexpr int B = decltype(Bc)::value;
    if (T + 1 < nt) STAGE(B ^ 1, T + 1);
    bool act = (!masked) || (T * 64 <= qmax_w);
    if (act) {
      // ---- S^T = K * Q^T (64s x 32q) ----
      fx16 s0v = {}, s1v = {};
#pragma unroll
      for (int ds = 0; ds < 4; ++ds) {
        frag8 k0 = *(const frag8*)(LDS + B * 8192 + (aK ^ (ds << 5)));
        frag8 k1 = *(const frag8*)(LDS + B * 8192 + 4096 + (aK ^ (ds << 5)));
        s0v = MFMA32(k0, qf[ds], s0v);
        s1v = MFMA32(k1, qf[ds], s1v);
      }
      // ---- causal mask (diagonal tiles only) ----
      if (masked && T * 64 + 63 > qmin_w) {
#pragma unroll
        for (int g = 0; g < 4; ++g)
#pragma unroll
          for (int r = 0; r < 4; ++r) {
            int sg = T * 64 + r + 8 * g + 4 * hi;
            if (sg > qrow) s0v[4 * g + r] = -__builtin_inff();
            if (sg + 32 > qrow) s1v[4 * g + r] = -__builtin_inff();
          }
      }
      // ---- online softmax (row q = l31, partner = lane^32) ----
      float mx = s0v[0];
#pragma unroll
      for (int i = 1; i < 16; ++i) mx = fmaxf(mx, s0v[i]);
#pragma unroll
      for (int i = 0; i < 16; ++i) mx = fmaxf(mx, s1v[i]);
      mx = fmaxf(mx, __int_as_float(__shfl_xor(__float_as_int(mx), 32)));
      if (!__all(mx <= m_run + 8.0f)) {   // defer-max (T13)
        float mn = fmaxf(m_run, mx);
        float al = __builtin_amdgcn_exp2f(m_run - mn);
#pragma unroll
        for (int i = 0; i < 16; ++i) { oa0[i] *= al; oa1[i] *= al; }
        l_run *= al;
        m_run = mn;
      }
      float ps = 0.f;
#pragma unroll
      for (int i = 0; i < 16; ++i) {
        s0v[i] = __builtin_amdgcn_exp2f(s0v[i] - m_run); ps += s0v[i];
      }
#pragma unroll
      for (int i = 0; i < 16; ++i) {
        s1v[i] = __builtin_amdgcn_exp2f(s1v[i] - m_run); ps += s1v[i];
      }
      ps += __int_as_float(__shfl_xor(__float_as_int(ps), 32));
      l_run += ps;
      // ---- O^T += V^T * P  (4 k-tiles of 16 s) ----
#pragma unroll
      for (int kt = 0; kt < 4; ++kt) {
        const int b8 = (kt & 1) * 8;
        float p0, p1, p2, p3, p4, p5, p6, p7;
        if (kt < 2) { p0=s0v[b8+0];p1=s0v[b8+1];p2=s0v[b8+2];p3=s0v[b8+3];p4=s0v[b8+4];p5=s0v[b8+5];p6=s0v[b8+6];p7=s0v[b8+7]; }
        else        { p0=s1v[b8+0];p1=s1v[b8+1];p2=s1v[b8+2];p3=s1v[b8+3];p4=s1v[b8+4];p5=s1v[b8+5];p6=s1v[b8+6];p7=s1v[b8+7]; }
        u32 X0 = cvtpk(p0, p1), X1 = cvtpk(p2, p3);
        u32 Y0 = cvtpk(p4, p5), Y1 = cvtpk(p6, p7);
        u32 sel0 = hi ? X0 : Y0, sel1 = hi ? X1 : Y1;
        u32 got0 = (u32)__shfl_xor((int)sel0, 32);
        u32 got1 = (u32)__shfl_xor((int)sel1, 32);
        union { u32 u[4]; frag8 f; } pf;
        pf.u[0] = hi ? got0 : X0;
        pf.u[1] = hi ? got1 : X1;
        pf.u[2] = hi ? Y0 : got0;
        pf.u[3] = hi ? Y1 : got1;
        frag8 v0 = *(const frag8*)(LDS + 16384 + B * 8192 + (aK ^ (kt << 5)));
        frag8 v1 = *(const frag8*)(LDS + 16384 + B * 8192 + 4096 + (aK ^ (kt << 5)));
        oa0 = MFMA32(v0, pf.f, oa0);
        oa1 = MFMA32(v1, pf.f, oa1);
      }
    }
    asm volatile("s_waitcnt vmcnt(0)" ::: "memory");
    __builtin_amdgcn_s_barrier();
  };

  STAGE(0, 0);
  asm volatile("s_waitcnt vmcnt(0)" ::: "memory");
  __builtin_amdgcn_s_barrier();
  int t = 0;
  while (true) {
    TILE(std::integral_constant<int, 0>{}, t); ++t; if (t >= nt) break;
    TILE(std::integral_constant<int, 1>{}, t); ++t; if (t >= nt) break;
  }

  // ---- epilogue: normalize + write O[q][d] ----
  float inv = 1.0f / l_run;
  int b = bh >> 4, hh = bh & 15;
  u16* orow = Ao + ((size_t)b * 2048 + qrow) * 1024 + hh * 64;
#pragma unroll
  for (int g = 0; g < 4; ++g) {
    int d0 = 8 * g + 4 * hi;
    u32 wA = cvtpk(oa0[4 * g + 0] * inv, oa0[4 * g + 1] * inv);
    u32 wB = cvtpk(oa0[4 * g + 2] * inv, oa0[4 * g + 3] * inv);
    u32 wC = cvtpk(oa1[4 * g + 0] * inv, oa1[4 * g + 1] * inv);
    u32 wD = cvtpk(oa1[4 * g + 2] * inv, oa1[4 * g + 3] * inv);
    *(u32*)(orow + d0 + 0) = wA;
    *(u32*)(orow + d0 + 2) = wB;
    *(u32*)(orow + d0 + 32) = wC;
    *(u32*)(orow + d0 + 34) = wD;
  }
}

// ---------------- launch ----------------

extern "C" void kernel_launch(void* const* d_in, const int* in_sizes, int n_in,
                              void* d_out, int out_size, void* d_ws, size_t ws_size,
                              hipStream_t stream) {
  const float* x = (const float*)d_in[0];
  const float* Wq = (const float*)d_in[1];
  const float* Wk = (const float*)d_in[2];
  const float* Wv = (const float*)d_in[3];
  const float* Wp = (const float*)d_in[4];
  const float* bp = (const float*)d_in[5];
  const int* is_masked = (const int*)d_in[6];
  float* out = (float*)d_out;
  char* ws = (char*)d_ws;
  u16* Xbf = (u16*)(ws + 0);              // 16 MB (reused as VT after gemm256)
  u16* Wt  = (u16*)(ws + 16777216);       // 6 MB
  u16* Wpb = (u16*)(ws + 23068672);       // 2 MB
  u16* Qb  = (u16*)(ws + 25165824);       // 16 MB
  u16* Kb  = (u16*)(ws + 41943040);       // 16 MB
  u16* Vb  = (u16*)(ws + 58720256);       // 16 MB
  u16* Ao  = (u16*)(ws + 75497472);       // 16 MB
  u16* VTg = Xbf;                         // alias: Xbf dead after gemm256

  cvt_x<<<2048, 256, 0, stream>>>(x, Xbf);
  cvt_wqkv<<<dim3(48, 16), 256, 0, stream>>>(Wq, Wk, Wv, Wt);
  cvt_wp<<<1024, 256, 0, stream>>>(Wp, Wpb);
  gemm256<<<512, 512, 0, stream>>>(Xbf, Wt, Qb, Kb, Vb);
  transpose_v<<<dim3(64, 32), 256, 0, stream>>>(Vb, VTg);
  attn<<<dim3(64, 16), 256, 0, stream>>>(Qb, Kb, VTg, Ao, is_masked);
  gemm_proj<<<dim3(64, 8), 256, 0, stream>>>(Ao, Wpb, out, bp);
}

// Round 5
// 161.219 us; speedup vs baseline: 2.1046x; 1.0331x over previous
//
#include <hip/hip_runtime.h>
#include <stdint.h>
#include <type_traits>

typedef unsigned short u16;
typedef unsigned int u32;
typedef __attribute__((ext_vector_type(8))) short frag8;   // 8 bf16 (4 VGPRs)
typedef __attribute__((ext_vector_type(4))) float fx4;     // 4 fp32 acc
typedef __attribute__((ext_vector_type(16))) float fx16;   // 16 fp32 acc (32x32)

#define MFMA(a, b, c) __builtin_amdgcn_mfma_f32_16x16x32_bf16((a), (b), (c), 0, 0, 0)
#define MFMA32(a, b, c) __builtin_amdgcn_mfma_f32_32x32x16_bf16((a), (b), (c), 0, 0, 0)

__device__ __forceinline__ void gload16(const void* g, void* l) {
  __builtin_amdgcn_global_load_lds((const __attribute__((address_space(1))) void*)g,
                                   (__attribute__((address_space(3))) void*)l, 16, 0, 0);
}

__device__ __forceinline__ u16 f2bf(float f) {
  union { float f; unsigned int u; } c; c.f = f;
  unsigned int r = c.u + 0x7FFFu + ((c.u >> 16) & 1u);  // RNE
  return (u16)(r >> 16);
}

__device__ __forceinline__ u32 cvtpk(float lo, float hi) {
  u32 r;
  asm("v_cvt_pk_bf16_f32 %0, %1, %2" : "=v"(r) : "v"(lo), "v"(hi));
  return r;
}

// ---------------- conversions ----------------

__global__ __launch_bounds__(256) void cvt_x(const float* __restrict__ x, u16* __restrict__ xb) {
  const int n4 = (8192 * 1024) / 4;
  for (int i = blockIdx.x * 256 + threadIdx.x; i < n4; i += 2048 * 256) {
    float4 v = ((const float4*)x)[i];
    ushort4 o;
    o.x = f2bf(v.x); o.y = f2bf(v.y); o.z = f2bf(v.z); o.w = f2bf(v.w);
    ((ushort4*)xb)[i] = o;
  }
}

// Wq/Wk/Wv [H][C][D] -> Wt [(type*16+h)*64+d][c]  (N=3072 rows, K=1024)
__global__ __launch_bounds__(256) void cvt_wqkv(const float* __restrict__ Wq,
                                                const float* __restrict__ Wk,
                                                const float* __restrict__ Wv,
                                                u16* __restrict__ Wt) {
  __shared__ u16 Tls[64][72];  // +pad
  int hh = blockIdx.x;            // 0..47
  int c0 = blockIdx.y * 64;
  int type = hh >> 4, h = hh & 15;
  const float* Wsrc = (type == 0 ? Wq : (type == 1 ? Wk : Wv)) + (size_t)h * 1024 * 64;
  int t = threadIdx.x;
  int cr = t >> 4, q4 = (t & 15) * 4;
  for (int i = 0; i < 4; ++i) {
    int c = cr + i * 16;
    float4 v = *(const float4*)(Wsrc + (size_t)(c0 + c) * 64 + q4);
    Tls[q4 + 0][c] = f2bf(v.x);
    Tls[q4 + 1][c] = f2bf(v.y);
    Tls[q4 + 2][c] = f2bf(v.z);
    Tls[q4 + 3][c] = f2bf(v.w);
  }
  __syncthreads();
  for (int i = 0; i < 4; ++i) {
    int d = cr + i * 16;
    ushort4 o;
    o.x = Tls[d][q4 + 0]; o.y = Tls[d][q4 + 1]; o.z = Tls[d][q4 + 2]; o.w = Tls[d][q4 + 3];
    *(ushort4*)(Wt + ((size_t)hh * 64 + d) * 1024 + c0 + q4) = o;
  }
}

__global__ __launch_bounds__(256) void cvt_wp(const float* __restrict__ Wp, u16* __restrict__ wb) {
  const int n4 = (1024 * 1024) / 4;
  for (int i = blockIdx.x * 256 + threadIdx.x; i < n4; i += 1024 * 256) {
    float4 v = ((const float4*)Wp)[i];
    ushort4 o;
    o.x = f2bf(v.x); o.y = f2bf(v.y); o.z = f2bf(v.z); o.w = f2bf(v.w);
    ((ushort4*)wb)[i] = o;
  }
}

// V [bh][2048][64] -> VT [bh][64][2048]
__global__ __launch_bounds__(256) void transpose_v(const u16* __restrict__ Vb, u16* __restrict__ VTg) {
  __shared__ u16 T[64 * 64];  // chunk-XOR swizzled rows of 128B
  int bh = blockIdx.x, t0 = blockIdx.y * 64;
  const u16* src = Vb + ((size_t)bh * 2048 + t0) * 64;
  int tid = threadIdx.x;
  int tl = tid >> 2, c16 = (tid & 3) * 16;
  int swzw = (tl & 7) << 4;
  frag8 a = *(const frag8*)(src + (size_t)tl * 64 + c16);
  frag8 b = *(const frag8*)(src + (size_t)tl * 64 + c16 + 8);
  *(frag8*)((char*)T + tl * 128 + ((c16 * 2) ^ swzw)) = a;
  *(frag8*)((char*)T + tl * 128 + ((c16 * 2 + 16) ^ swzw)) = b;
  __syncthreads();
  int d_ = tid & 63;
#pragma unroll
  for (int k = 0; k < 2; ++k) {
    int c_ = (tid >> 6) + 4 * k;
    frag8 o;
#pragma unroll
    for (int j = 0; j < 8; ++j) {
      int t = c_ * 8 + j;
      o[j] = *(const u16*)((const char*)T + t * 128 + ((2 * d_) ^ ((t & 7) << 4)));
    }
    *(frag8*)(VTg + ((size_t)bh * 64 + d_) * 2048 + t0 + c_ * 8) = o;
  }
}

// ---------------- GEMM: BM=256, BN=192/128, BK=64, 512 thr, counted-vmcnt pipeline ----------------
// A double-buffered (staged at phase 0 for t+1), B TRIPLE-buffered (staged at phases 2,3 for t+2).
// Per-tile wait = vmcnt(NB): retires A(t+1)+B(t+1), keeps B(t+2) in flight. Never drains mid-loop.

template <int BN, int MODE>
__global__ __launch_bounds__(512, 2) void gemm2(const u16* __restrict__ A, const u16* __restrict__ Bw,
                                                u16* __restrict__ Qb, u16* __restrict__ Kb,
                                                u16* __restrict__ Vb, float* __restrict__ outp,
                                                const float* __restrict__ bp) {
  constexpr int NI = BN / 64;       // per-wave ni count (wave tile 128 x BN/4)
  constexpr int NB = BN / 64;       // B gloads per K-tile
  constexpr int BBYTES = BN * 128;  // one B buffer
  __shared__ __align__(16) char LDSC[65536 + 3 * BBYTES];
  const int tid = threadIdx.x, w = tid >> 6, lane = tid & 63;
  const int lr = lane & 15, lg = lane >> 4;
  // bijective XCD-chunked swizzle (grid = 32 * (3072or1024/BN), multiple of 8)
  constexpr int NBY = (BN == 192) ? 16 : 8;
  const int wg = blockIdx.x;
  const int xcd = wg & 7, loc = wg >> 3;
  const int bx = xcd * 4 + loc / NBY;
  const int by = loc % NBY;
  const int m0 = bx * 256, n0 = by * BN;
  // staging source/dest (linear LDS dest, inverse-XOR-swizzled global chunk)
  const int r8 = lane >> 3;
  const int c8 = ((lane & 7) ^ r8) * 8;  // u16 offset
  const u16* aS[4];
  const u16* bS[NB];
#pragma unroll
  for (int l = 0; l < 4; ++l) aS[l] = A + (size_t)(m0 + l * 64 + w * 8 + r8) * 1024 + c8;
#pragma unroll
  for (int l = 0; l < NB; ++l) bS[l] = Bw + (size_t)(n0 + l * 64 + w * 8 + r8) * 1024 + c8;
  const int wmB = (w >> 2) * 128, wnB = (w & 3) * (BN / 4);

  auto rdA = [&](const char* ab, int mi, int ks) -> frag8 {
    int row = wmB + mi * 16 + lr;
    return *(const frag8*)(ab + row * 128 + ((((ks << 2) + lg) ^ (lr & 7)) << 4));
  };
  auto rdB = [&](const char* bbuf, int ni, int ks) -> frag8 {
    int row = wnB + ni * 16 + lr;
    return *(const frag8*)(bbuf + row * 128 + ((((ks << 2) + lg) ^ (lr & 7)) << 4));
  };

  fx4 acc[8][NI] = {};

  // prologue: stage A(0), B(0), B(1); wait all but B(1); barrier
#pragma unroll
  for (int l = 0; l < 4; ++l) gload16(aS[l], LDSC + l * 8192 + w * 1024);
#pragma unroll
  for (int l = 0; l < NB; ++l) gload16(bS[l], LDSC + 65536 + l * 8192 + w * 1024);
#pragma unroll
  for (int l = 0; l < NB; ++l) gload16(bS[l] + 64, LDSC + 65536 + BBYTES + l * 8192 + w * 1024);
  if constexpr (NB == 3) asm volatile("s_waitcnt vmcnt(3)" ::: "memory");
  else asm volatile("s_waitcnt vmcnt(2)" ::: "memory");
  __builtin_amdgcn_s_barrier();

  for (int t = 0; t < 16; ++t) {
    const char* ab = LDSC + (t & 1) * 32768;
    const char* bb = LDSC + 65536 + (t % 3) * BBYTES;
    char* abN = LDSC + ((t + 1) & 1) * 32768;
    char* bbN = LDSC + 65536 + ((t + 2) % 3) * BBYTES;
    frag8 bfr[NI][2];
#pragma unroll
    for (int q = 0; q < 4; ++q) {
      if (q == 0) {
#pragma unroll
        for (int ni = 0; ni < NI; ++ni) {
          bfr[ni][0] = rdB(bb, ni, 0);
          bfr[ni][1] = rdB(bb, ni, 1);
        }
      }
      frag8 a00 = rdA(ab, 2 * q + 0, 0), a01 = rdA(ab, 2 * q + 0, 1);
      frag8 a10 = rdA(ab, 2 * q + 1, 0), a11 = rdA(ab, 2 * q + 1, 1);
      if (q == 0 && t + 1 < 16) {
#pragma unroll
        for (int l = 0; l < 4; ++l) gload16(aS[l] + (t + 1) * 64, abN + l * 8192 + w * 1024);
      }
      if (q == 2 && t + 2 < 16) {
        gload16(bS[0] + (t + 2) * 64, bbN + 0 * 8192 + w * 1024);
        gload16(bS[1] + (t + 2) * 64, bbN + 1 * 8192 + w * 1024);
      }
      if (q == 3 && t + 2 < 16 && NB == 3) {
        gload16(bS[2] + (t + 2) * 64, bbN + 2 * 8192 + w * 1024);
      }
      __builtin_amdgcn_s_barrier();
      __builtin_amdgcn_s_setprio(1);
#pragma unroll
      for (int ni = 0; ni < NI; ++ni) {
        acc[2 * q + 0][ni] = MFMA(a00, bfr[ni][0], acc[2 * q + 0][ni]);
        acc[2 * q + 0][ni] = MFMA(a01, bfr[ni][1], acc[2 * q + 0][ni]);
        acc[2 * q + 1][ni] = MFMA(a10, bfr[ni][0], acc[2 * q + 1][ni]);
        acc[2 * q + 1][ni] = MFMA(a11, bfr[ni][1], acc[2 * q + 1][ni]);
      }
      __builtin_amdgcn_s_setprio(0);
      if (q == 3) {
        if (t < 14) {
          if constexpr (NB == 3) asm volatile("s_waitcnt vmcnt(3)" ::: "memory");
          else asm volatile("s_waitcnt vmcnt(2)" ::: "memory");
        } else {
          asm volatile("s_waitcnt vmcnt(0)" ::: "memory");
        }
      }
      __builtin_amdgcn_s_barrier();
    }
  }

  // epilogue
#pragma unroll
  for (int mi = 0; mi < 8; ++mi)
#pragma unroll
    for (int r = 0; r < 4; ++r) {
      int m = m0 + wmB + mi * 16 + lg * 4 + r;
      if (MODE == 0) {
        int b = m >> 11, tt = m & 2047;
#pragma unroll
        for (int ni = 0; ni < NI; ++ni) {
          int n = n0 + wnB + ni * 16 + lr;
          int type = n >> 10, h = (n >> 6) & 15, d = n & 63;
          u16* dst = (type == 0) ? Qb : ((type == 1) ? Kb : Vb);
          float v = acc[mi][ni][r];
          if (type == 0) v *= 0.04508422002778011f;  // log2(e)/32 folded into Q
          dst[((size_t)(b * 16 + h) * 2048 + tt) * 64 + d] = f2bf(v);
        }
      } else {
#pragma unroll
        for (int ni = 0; ni < NI; ++ni) {
          int n = n0 + wnB + ni * 16 + lr;
          outp[(size_t)m * 1024 + n] = acc[mi][ni][r] + bp[n];
        }
      }
    }
}

// ---------------- flash attention: 32x32 MFMA, q in lane&31, 2-phase pipeline ----------------
// grid (bh=64, 16); block = 128 q-rows, 4 waves x 32 q. KV tile 64, double-buffered.

__global__ __launch_bounds__(256, 4) void attn(const u16* __restrict__ Qb, const u16* __restrict__ Kb,
                                               const u16* __restrict__ VTg, u16* __restrict__ Ao,
                                               const int* __restrict__ mflag) {
  // LDS map (bytes): K buf0 @0, K buf1 @8192, V buf0 @16384, V buf1 @24576
  __shared__ __align__(16) char LDS[32768];
  const int tid = threadIdx.x, w = tid >> 6, lane = tid & 63;
  const int l31 = lane & 31, hi = lane >> 5;
  const int bh = blockIdx.x;
  const int qt = 15 - (int)blockIdx.y;   // big blocks first
  const int masked = mflag[0];
  const int qbase = qt * 128;
  const u16* Qh = Qb + (size_t)bh * (2048 * 64);
  const u16* Kh = Kb + (size_t)bh * (2048 * 64);
  const u16* Vh = VTg + (size_t)bh * (64 * 2048);
  const int qrow = qbase + w * 32 + l31;
  frag8 qf[4];
#pragma unroll
  for (int s = 0; s < 4; ++s) qf[s] = *(const frag8*)(Qh + (size_t)qrow * 64 + s * 16 + hi * 8);
  // staging (global_load_lds): call c covers rows c*8..c*8+7; lane chunk pre-swizzled
  const int srow = lane >> 3;
  const int schunk = ((lane & 7) ^ srow) * 8;
  const int c0 = w * 2, c1 = w * 2 + 1;
  const u16* kg0 = Kh + (size_t)(c0 * 8 + srow) * 64 + schunk;
  const u16* kg1 = Kh + (size_t)(c1 * 8 + srow) * 64 + schunk;
  const u16* vg0 = Vh + (size_t)(c0 * 8 + srow) * 2048 + schunk;
  const u16* vg1 = Vh + (size_t)(c1 * 8 + srow) * 2048 + schunk;
  // LDS read base (byte): row l31 (+slab*4096), chunk XOR swizzle
  const int aK = l31 * 128 + ((hi * 16) ^ ((l31 & 7) << 4));
  const int qmax_w = qbase + w * 32 + 31;
  const int qmin_w = qbase + w * 32;
  float m_run = -__builtin_inff(), l_run = 0.f;
  fx16 oa0 = {}, oa1 = {};
  const int nt = masked ? (2 * qt + 2) : 32;

  auto STAGE = [&](int B, int T) {
    size_t ko = (size_t)T * 4096, vo = (size_t)T * 64;
    gload16(kg0 + ko, LDS + B * 8192 + c0 * 1024);
    gload16(kg1 + ko, LDS + B * 8192 + c1 * 1024);
    gload16(vg0 + vo, LDS + 16384 + B * 8192 + c0 * 1024);
    gload16(vg1 + vo, LDS + 16384 + B * 8192 + c1 * 1024);
  };

  auto TILE = [&](auto Bc, int T) {
    constexpr int B = decltype(Bc)::value;
    if (T + 1 < nt) STAGE(B ^ 1, T + 1);
    bool act = (!masked) || (T * 64 <= qmax_w);
    if (act) {
      // ---- S^T = K * Q^T (64s x 32q) ----
      fx16 s0v = {}, s1v = {};
#pragma unroll
      for (int ds = 0; ds < 4; ++ds) {
        frag8 k0 = *(const frag8*)(LDS + B * 8192 + (aK ^ (ds << 5)));
        frag8 k1 = *(const frag8*)(LDS + B * 8192 + 4096 + (aK ^ (ds << 5)));
        s0v = MFMA32(k0, qf[ds], s0v);
        s1v = MFMA32(k1, qf[ds], s1v);
      }
      // ---- causal mask (diagonal tiles only) ----
      if (masked && T * 64 + 63 > qmin_w) {
#pragma unroll
        for (int g = 0; g < 4; ++g)
#pragma unroll
          for (int r = 0; r < 4; ++r) {
            int sg = T * 64 + r + 8 * g + 4 * hi;
            if (sg > qrow) s0v[4 * g + r] = -__builtin_inff();
            if (sg + 32 > qrow) s1v[4 * g + r] = -__builtin_inff();
          }
      }
      // ---- online softmax (row q = l31, partner = lane^32) ----
      float mx = s0v[0];
#pragma unroll
      for (int i = 1; i < 16; ++i) mx = fmaxf(mx, s0v[i]);
#pragma unroll
      for (int i = 0; i < 16; ++i) mx = fmaxf(mx, s1v[i]);
      mx = fmaxf(mx, __int_as_float(__shfl_xor(__float_as_int(mx), 32)));
      if (!__all(mx <= m_run + 8.0f)) {   // defer-max (T13)
        float mn = fmaxf(m_run, mx);
        float al = __builtin_amdgcn_exp2f(m_run - mn);
#pragma unroll
        for (int i = 0; i < 16; ++i) { oa0[i] *= al; oa1[i] *= al; }
        l_run *= al;
        m_run = mn;
      }
      float ps = 0.f;
#pragma unroll
      for (int i = 0; i < 16; ++i) {
        s0v[i] = __builtin_amdgcn_exp2f(s0v[i] - m_run); ps += s0v[i];
      }
#pragma unroll
      for (int i = 0; i < 16; ++i) {
        s1v[i] = __builtin_amdgcn_exp2f(s1v[i] - m_run); ps += s1v[i];
      }
      ps += __int_as_float(__shfl_xor(__float_as_int(ps), 32));
      l_run += ps;
      // ---- O^T += V^T * P  (4 k-tiles of 16 s) ----
#pragma unroll
      for (int kt = 0; kt < 4; ++kt) {
        const int b8 = (kt & 1) * 8;
        float p0, p1, p2, p3, p4, p5, p6, p7;
        if (kt < 2) { p0=s0v[b8+0];p1=s0v[b8+1];p2=s0v[b8+2];p3=s0v[b8+3];p4=s0v[b8+4];p5=s0v[b8+5];p6=s0v[b8+6];p7=s0v[b8+7]; }
        else        { p0=s1v[b8+0];p1=s1v[b8+1];p2=s1v[b8+2];p3=s1v[b8+3];p4=s1v[b8+4];p5=s1v[b8+5];p6=s1v[b8+6];p7=s1v[b8+7]; }
        u32 X0 = cvtpk(p0, p1), X1 = cvtpk(p2, p3);
        u32 Y0 = cvtpk(p4, p5), Y1 = cvtpk(p6, p7);
        u32 sel0 = hi ? X0 : Y0, sel1 = hi ? X1 : Y1;
        u32 got0 = (u32)__shfl_xor((int)sel0, 32);
        u32 got1 = (u32)__shfl_xor((int)sel1, 32);
        union { u32 u[4]; frag8 f; } pf;
        pf.u[0] = hi ? got0 : X0;
        pf.u[1] = hi ? got1 : X1;
        pf.u[2] = hi ? Y0 : got0;
        pf.u[3] = hi ? Y1 : got1;
        frag8 v0 = *(const frag8*)(LDS + 16384 + B * 8192 + (aK ^ (kt << 5)));
        frag8 v1 = *(const frag8*)(LDS + 16384 + B * 8192 + 4096 + (aK ^ (kt << 5)));
        oa0 = MFMA32(v0, pf.f, oa0);
        oa1 = MFMA32(v1, pf.f, oa1);
      }
    }
    asm volatile("s_waitcnt vmcnt(0)" ::: "memory");
    __builtin_amdgcn_s_barrier();
  };

  STAGE(0, 0);
  asm volatile("s_waitcnt vmcnt(0)" ::: "memory");
  __builtin_amdgcn_s_barrier();
  int t = 0;
  while (true) {
    TILE(std::integral_constant<int, 0>{}, t); ++t; if (t >= nt) break;
    TILE(std::integral_constant<int, 1>{}, t); ++t; if (t >= nt) break;
  }

  // ---- epilogue: normalize + write O[q][d] ----
  float inv = 1.0f / l_run;
  int b = bh >> 4, hh = bh & 15;
  u16* orow = Ao + ((size_t)b * 2048 + qrow) * 1024 + hh * 64;
#pragma unroll
  for (int g = 0; g < 4; ++g) {
    int d0 = 8 * g + 4 * hi;
    u32 wA = cvtpk(oa0[4 * g + 0] * inv, oa0[4 * g + 1] * inv);
    u32 wB = cvtpk(oa0[4 * g + 2] * inv, oa0[4 * g + 3] * inv);
    u32 wC = cvtpk(oa1[4 * g + 0] * inv, oa1[4 * g + 1] * inv);
    u32 wD = cvtpk(oa1[4 * g + 2] * inv, oa1[4 * g + 3] * inv);
    *(u32*)(orow + d0 + 0) = wA;
    *(u32*)(orow + d0 + 2) = wB;
    *(u32*)(orow + d0 + 32) = wC;
    *(u32*)(orow + d0 + 34) = wD;
  }
}

// ---------------- launch ----------------

extern "C" void kernel_launch(void* const* d_in, const int* in_sizes, int n_in,
                              void* d_out, int out_size, void* d_ws, size_t ws_size,
                              hipStream_t stream) {
  const float* x = (const float*)d_in[0];
  const float* Wq = (const float*)d_in[1];
  const float* Wk = (const float*)d_in[2];
  const float* Wv = (const float*)d_in[3];
  const float* Wp = (const float*)d_in[4];
  const float* bp = (const float*)d_in[5];
  const int* is_masked = (const int*)d_in[6];
  float* out = (float*)d_out;
  char* ws = (char*)d_ws;
  u16* Xbf = (u16*)(ws + 0);              // 16 MB (reused as VT after gemm)
  u16* Wt  = (u16*)(ws + 16777216);       // 6 MB
  u16* Wpb = (u16*)(ws + 23068672);       // 2 MB
  u16* Qb  = (u16*)(ws + 25165824);       // 16 MB
  u16* Kb  = (u16*)(ws + 41943040);       // 16 MB
  u16* Vb  = (u16*)(ws + 58720256);       // 16 MB
  u16* Ao  = (u16*)(ws + 75497472);       // 16 MB
  u16* VTg = Xbf;                         // alias: Xbf dead after gemm

  cvt_x<<<2048, 256, 0, stream>>>(x, Xbf);
  cvt_wqkv<<<dim3(48, 16), 256, 0, stream>>>(Wq, Wk, Wv, Wt);
  cvt_wp<<<1024, 256, 0, stream>>>(Wp, Wpb);
  gemm2<192, 0><<<512, 512, 0, stream>>>(Xbf, Wt, Qb, Kb, Vb, nullptr, nullptr);
  transpose_v<<<dim3(64, 32), 256, 0, stream>>>(Vb, VTg);
  attn<<<dim3(64, 16), 256, 0, stream>>>(Qb, Kb, VTg, Ao, is_masked);
  gemm2<128, 1><<<256, 512, 0, stream>>>(Ao, Wpb, nullptr, nullptr, nullptr, out, bp);
}